// Round 15
// baseline (138.717 us; speedup 1.0000x reference)
//
#include <hip/hip_runtime.h>
#include <hip/hip_bf16.h>

#define DM 1024
#define NH 16
#define DKH 64
#define BB 2
#define SS 2048
#define MM (BB*SS)   // 4096
#define HKB 1024     // KV half length

typedef __bf16 v8bf __attribute__((ext_vector_type(8)));
typedef float  v4f  __attribute__((ext_vector_type(4)));
typedef float  v16f __attribute__((ext_vector_type(16)));

__device__ __forceinline__ unsigned short f2bf(float f) {
    union { float f; unsigned int u; } v; v.f = f;
    unsigned int u = v.u;
    unsigned int r = (u + 0x7fffu + ((u >> 16) & 1u)) >> 16;
    return (unsigned short)r;
}

__device__ __forceinline__ int cvtpk(float lo, float hi) {
    int r;
    asm("v_cvt_pk_bf16_f32 %0, %1, %2" : "=v"(r) : "v"(lo), "v"(hi));
    return r;
}

__device__ __forceinline__ void pl32swap(int& a, int& b) {
    asm("v_permlane32_swap_b32 %0, %1" : "+v"(a), "+v"(b));
}

__device__ __forceinline__ void gl16(const void* g, void* l) {
    auto gp = reinterpret_cast<const __attribute__((address_space(1))) unsigned int*>(
        reinterpret_cast<uintptr_t>(g));
    auto lp = reinterpret_cast<__attribute__((address_space(3))) unsigned int*>(
        reinterpret_cast<uintptr_t>(l));
    __builtin_amdgcn_global_load_lds(gp, lp, 16, 0, 0);
}

// ---------------- fp32 -> bf16 one-shot convert: [xq|xk|xv] then [wq|wk|wv|wo] -----------
__global__ __launch_bounds__(256) void cvt_to_bf16(
    const float* __restrict__ xq, const float* __restrict__ xk, const float* __restrict__ xv,
    const float* __restrict__ wq, const float* __restrict__ wk, const float* __restrict__ wv,
    const float* __restrict__ wo, unsigned short* __restrict__ dst)
{
    const int y = blockIdx.y;
    const float* src;
    size_t n, off;
    if (y < 3) {
        src = (y == 0) ? xq : (y == 1) ? xk : xv;
        n = (size_t)MM * DM;
        off = (size_t)y * MM * DM;
    } else {
        src = (y == 3) ? wq : (y == 4) ? wk : (y == 5) ? wv : wo;
        n = (size_t)DM * DM;
        off = (size_t)3 * MM * DM + (size_t)(y - 3) * DM * DM;
    }
    unsigned short* d = dst + off;
    const size_t stride = (size_t)gridDim.x * blockDim.x;
    for (size_t i = (size_t)blockIdx.x * blockDim.x + threadIdx.x; i * 8 < n; i += stride) {
        float4 a = ((const float4*)src)[2 * i];
        float4 b = ((const float4*)src)[2 * i + 1];
        uint4 o;
        o.x = (unsigned)cvtpk(a.x, a.y);
        o.y = (unsigned)cvtpk(a.z, a.w);
        o.z = (unsigned)cvtpk(b.x, b.y);
        o.w = (unsigned)cvtpk(b.z, b.w);
        ((uint4*)d)[i] = o;
    }
}

// ---------------- QKV projection: 256x256 tile, 8-phase chunk-ring pipeline (T3+T4) -------
// z=0: Q (scaled by 0.125*log2e, layout [bh][s][64]); z=1: K; z=2: V^T ([bh][64][s])
// Chunk c (16KB = 256 rows x 32 K): tile=c>>2, khalf=(c>>1)&1, B-side=c&1. 8-slot LDS ring.
__global__ __launch_bounds__(512, 2) void proj_qkv_8p(
    const unsigned short* __restrict__ xb, const unsigned short* __restrict__ wb,
    const float* __restrict__ bq, const float* __restrict__ bk, const float* __restrict__ bv,
    unsigned short* __restrict__ q_ws, unsigned short* __restrict__ k_ws,
    unsigned short* __restrict__ vt_ws)
{
    const int z = blockIdx.z;
    const unsigned short* X = xb + (size_t)z * MM * DM;
    const unsigned short* W = wb + (size_t)z * DM * DM;
    const float* bias = (z == 0) ? bq : (z == 1) ? bk : bv;

    __shared__ unsigned short ls[8][8192];   // 8 x 16KB = 128KB ring

    const int t = threadIdx.x;               // 0..511
    const int lane = t & 63, w = t >> 6;     // 8 waves
    const int wm = w >> 2, wn = w & 3;       // 2M x 4N
    const int g = lane >> 4, lr = lane & 15;

    // XCD swizzle: 64 blocks/z; xcd owns 2 M-panels x 4 N-panels
    const int hid = blockIdx.y * 8 + blockIdx.x;
    const int xcd = hid & 7, slot = hid >> 3;        // slot 0..7
    const int mbase = (xcd * 2 + (slot & 1)) * 256;  // 16 M-panels
    const int nbase = (slot >> 1) * 256;             // 4 N-panels

    v4f acc[8][4];
#pragma unroll
    for (int i = 0; i < 8; ++i)
#pragma unroll
        for (int j = 0; j < 4; ++j)
            acc[i][j] = (v4f){0.f, 0.f, 0.f, 0.f};

    // stage chunk c: 2 gl16/thread; chunklet j: row=j>>2, col8=(j&3)*8 within 32-K slice
    auto stage = [&](int c) {
        const int kt = c >> 2, kh = (c >> 1) & 1;
        const unsigned short* src = (c & 1) ? W : X;
        const int base = (c & 1) ? nbase : mbase;
        unsigned short* dst = &ls[c & 7][0];
        const int j0 = t, j1 = t + 512;
        gl16(src + (size_t)(base + (j0 >> 2)) * DM + kt * 64 + kh * 32 + (j0 & 3) * 8,
             dst + j0 * 8);
        gl16(src + (size_t)(base + (j1 >> 2)) * DM + kt * 64 + kh * 32 + (j1 & 3) * 8,
             dst + j1 * 8);
    };

#define PQ_PAIR(PP, VMINSTR, STE, STO) { \
    asm volatile(VMINSTR ::: "memory"); \
    __builtin_amdgcn_sched_barrier(0); \
    __builtin_amdgcn_s_barrier(); \
    __builtin_amdgcn_sched_barrier(0); \
    if (STE) stage(2 * (PP) + 5); \
    const unsigned short* As = &ls[(2 * (PP)) & 7][0]; \
    const unsigned short* Bs = &ls[(2 * (PP) + 1) & 7][0]; \
    v8bf af[8], bf2[2]; \
    _Pragma("unroll") \
    for (int mt = 0; mt < 8; ++mt) \
        af[mt] = *(const v8bf*)&As[((wm * 128 + mt * 16 + lr) * 4 + g) * 8]; \
    _Pragma("unroll") \
    for (int nl = 0; nl < 2; ++nl) \
        bf2[nl] = *(const v8bf*)&Bs[((wn * 64 + nl * 16 + lr) * 4 + g) * 8]; \
    __builtin_amdgcn_s_setprio(1); \
    _Pragma("unroll") \
    for (int mt = 0; mt < 8; ++mt) \
        _Pragma("unroll") \
        for (int nl = 0; nl < 2; ++nl) \
            acc[mt][nl] = __builtin_amdgcn_mfma_f32_16x16x32_bf16(af[mt], bf2[nl], acc[mt][nl], 0, 0, 0); \
    __builtin_amdgcn_s_setprio(0); \
    __builtin_amdgcn_sched_barrier(0); \
    __builtin_amdgcn_s_barrier(); \
    __builtin_amdgcn_sched_barrier(0); \
    if (STO) stage(2 * (PP) + 6); \
    _Pragma("unroll") \
    for (int nl = 0; nl < 2; ++nl) \
        bf2[nl] = *(const v8bf*)&Bs[((wn * 64 + (2 + nl) * 16 + lr) * 4 + g) * 8]; \
    __builtin_amdgcn_s_setprio(1); \
    _Pragma("unroll") \
    for (int mt = 0; mt < 8; ++mt) \
        _Pragma("unroll") \
        for (int nl = 0; nl < 2; ++nl) \
            acc[mt][2 + nl] = __builtin_amdgcn_mfma_f32_16x16x32_bf16(af[mt], bf2[nl], acc[mt][2 + nl], 0, 0, 0); \
    __builtin_amdgcn_s_setprio(0); \
}

    // prologue: chunks 0..4 in flight (10 loads/wave)
    stage(0); stage(1); stage(2); stage(3); stage(4);

#pragma unroll 1
    for (int pp = 0; pp < 29; ++pp) {
        PQ_PAIR(pp, "s_waitcnt vmcnt(6)", 1, 1)
    }
    PQ_PAIR(29, "s_waitcnt vmcnt(6)", 1, 0)   // stages chunk 63
    PQ_PAIR(30, "s_waitcnt vmcnt(4)", 0, 0)
    PQ_PAIR(31, "s_waitcnt vmcnt(0)", 0, 0)
#undef PQ_PAIR

    const float scale = (z == 0) ? 0.18033688011112042f : 1.0f;  // 0.125*log2(e) for Q
#pragma unroll
    for (int nt = 0; nt < 4; ++nt) {
        int e = nbase + wn * 64 + nt * 16 + lr;
        float bval = bias[e];
        int h = e >> 6, dk = e & 63;
#pragma unroll
        for (int mt = 0; mt < 8; ++mt) {
#pragma unroll
            for (int r = 0; r < 4; ++r) {
                int m = mbase + wm * 128 + mt * 16 + g * 4 + r;
                float val = (acc[mt][nt][r] + bval) * scale;
                unsigned short o = f2bf(val);
                int b = m >> 11, s = m & 2047;
                if (z == 2) {
                    vt_ws[((size_t)(b * NH + h) * DKH + dk) * SS + s] = o;
                } else {
                    unsigned short* dst = (z == 0) ? q_ws : k_ws;
                    dst[((size_t)(b * NH + h) * SS + s) * DKH + dk] = o;
                }
            }
        }
    }
}

// ------------- Flash attention v6: sm-split per kb (exp/pack kb1 overlaps PV kb0) ---------
#define KB 64
#define LDP 72
#define TILE 4608   // shorts per 64x64 tile with pad

__global__ __launch_bounds__(512, 4) void attn_kernel(
    const unsigned short* __restrict__ q_ws, const unsigned short* __restrict__ k_ws,
    const unsigned short* __restrict__ vt_ws, unsigned short* __restrict__ o_ws)
{
    __shared__ __align__(16) unsigned short lsBuf[2 * 4 * TILE];   // 73728 B

    const int t = threadIdx.x, l = t & 63, w = t >> 6;   // w 0..7
    const int h = l >> 5, ql = l & 31;
    const int qg = w >> 1, hf = w & 1;

    const int hid = blockIdx.x;
    const int slot = hid >> 3;
    const int bh = (hid & 7) * 4 + (slot & 3);
    const int qp = slot >> 2;              // 0..15, 128 q rows each
    const int q0 = qp * 128 + qg * 32;

    const unsigned short* Kb = k_ws + (size_t)bh * SS * DKH;
    const unsigned short* Vb = vt_ws + (size_t)bh * DKH * SS;

    v8bf qf[4];
#pragma unroll
    for (int c = 0; c < 4; ++c)
        qf[c] = *(const v8bf*)(q_ws + ((size_t)bh * SS + q0 + ql) * DKH + c * 16 + h * 8);

    v16f oT[2];
#pragma unroll
    for (int d = 0; d < 2; ++d)
#pragma unroll
        for (int r = 0; r < 16; ++r) oT[d][r] = 0.f;
    float l_lane = 0.f;
    const v16f z16 = {};

    const int r0s = t >> 3, c0s = (t & 7) * 8;
    uint4 k0r, k1r, v0r, v1r;

    k0r = *(const uint4*)(Kb + (size_t)(r0s) * DKH + c0s);
    v0r = *(const uint4*)(Vb + (size_t)r0s * SS + c0s);
    k1r = *(const uint4*)(Kb + (size_t)(HKB + r0s) * DKH + c0s);
    v1r = *(const uint4*)(Vb + (size_t)r0s * SS + HKB + c0s);
    {
        unsigned short* B0 = lsBuf;
        *(uint4*)&B0[0 * TILE + r0s * LDP + c0s] = k0r;
        *(uint4*)&B0[1 * TILE + r0s * LDP + c0s] = v0r;
        *(uint4*)&B0[2 * TILE + r0s * LDP + c0s] = k1r;
        *(uint4*)&B0[3 * TILE + r0s * LDP + c0s] = v1r;
    }
    k0r = *(const uint4*)(Kb + (size_t)(KB + r0s) * DKH + c0s);
    v0r = *(const uint4*)(Vb + (size_t)r0s * SS + KB + c0s);
    k1r = *(const uint4*)(Kb + (size_t)(HKB + KB + r0s) * DKH + c0s);
    v1r = *(const uint4*)(Vb + (size_t)r0s * SS + HKB + KB + c0s);
    asm volatile("s_waitcnt lgkmcnt(0)" ::: "memory");
    __builtin_amdgcn_sched_barrier(0);
    __builtin_amdgcn_s_barrier();
    __builtin_amdgcn_sched_barrier(0);

    const int NT = 16;
    int p = 0;
    for (int tt = 0; tt < NT; ++tt) {
        unsigned short* Kp = lsBuf + p * (4 * TILE) + hf * (2 * TILE);
        unsigned short* Vp = Kp + TILE;
        if (tt + 1 < NT) {
            unsigned short* Bn = lsBuf + (p ^ 1) * (4 * TILE);
            *(uint4*)&Bn[0 * TILE + r0s * LDP + c0s] = k0r;
            *(uint4*)&Bn[1 * TILE + r0s * LDP + c0s] = v0r;
            *(uint4*)&Bn[2 * TILE + r0s * LDP + c0s] = k1r;
            *(uint4*)&Bn[3 * TILE + r0s * LDP + c0s] = v1r;
        }
        if (tt + 2 < NT) {
            int kt2 = (tt + 2) * KB;
            k0r = *(const uint4*)(Kb + (size_t)(kt2 + r0s) * DKH + c0s);
            v0r = *(const uint4*)(Vb + (size_t)r0s * SS + kt2 + c0s);
            k1r = *(const uint4*)(Kb + (size_t)(HKB + kt2 + r0s) * DKH + c0s);
            v1r = *(const uint4*)(Vb + (size_t)r0s * SS + HKB + kt2 + c0s);
        }

        // ---- S^T = K . Q^T (zero-C first MFMA) ----
        v16f sT[2];
        __builtin_amdgcn_s_setprio(1);
#pragma unroll
        for (int kb = 0; kb < 2; ++kb) {
            v8bf kf = *(const v8bf*)&Kp[(kb * 32 + ql) * LDP + h * 8];
            sT[kb] = __builtin_amdgcn_mfma_f32_32x32x16_bf16(kf, qf[0], z16, 0, 0, 0);
        }
#pragma unroll
        for (int c = 1; c < 4; ++c)
#pragma unroll
            for (int kb = 0; kb < 2; ++kb) {
                v8bf kf = *(const v8bf*)&Kp[(kb * 32 + ql) * LDP + c * 16 + h * 8];
                sT[kb] = __builtin_amdgcn_mfma_f32_32x32x16_bf16(kf, qf[c], sT[kb], 0, 0, 0);
            }
        __builtin_amdgcn_s_setprio(0);

        // ---- sm-split: per-kb {exp -> pack -> PV} so kb1's VALU overlaps PV kb0 ----
        v8bf pfrag[4];
#pragma unroll
        for (int kb = 0; kb < 2; ++kb) {
            float rs0 = 0.f, rs1 = 0.f, rs2 = 0.f, rs3 = 0.f;
#pragma unroll
            for (int r = 0; r < 16; r += 4) {
                float e0 = __builtin_amdgcn_exp2f(sT[kb][r + 0]);
                float e1 = __builtin_amdgcn_exp2f(sT[kb][r + 1]);
                float e2 = __builtin_amdgcn_exp2f(sT[kb][r + 2]);
                float e3 = __builtin_amdgcn_exp2f(sT[kb][r + 3]);
                sT[kb][r + 0] = e0; sT[kb][r + 1] = e1;
                sT[kb][r + 2] = e2; sT[kb][r + 3] = e3;
                rs0 += e0; rs1 += e1; rs2 += e2; rs3 += e3;
            }
            l_lane += (rs0 + rs1) + (rs2 + rs3);

#pragma unroll
            for (int cc = 0; cc < 2; ++cc) {
                int A0 = cvtpk(sT[kb][8 * cc + 0], sT[kb][8 * cc + 1]);
                int A1 = cvtpk(sT[kb][8 * cc + 2], sT[kb][8 * cc + 3]);
                int B0 = cvtpk(sT[kb][8 * cc + 4], sT[kb][8 * cc + 5]);
                int B1 = cvtpk(sT[kb][8 * cc + 6], sT[kb][8 * cc + 7]);
                pl32swap(A0, B0);
                pl32swap(A1, B1);
                union { int i[4]; v8bf v; } u;
                u.i[0] = A0; u.i[1] = A1; u.i[2] = B0; u.i[3] = B1;
                pfrag[kb * 2 + cc] = u.v;
            }

            __builtin_amdgcn_s_setprio(1);
#pragma unroll
            for (int db = 0; db < 2; ++db)
#pragma unroll
                for (int cc = 0; cc < 2; ++cc) {
                    int c = kb * 2 + cc;
                    v8bf vf = *(const v8bf*)&Vp[(db * 32 + ql) * LDP + c * 16 + h * 8];
                    oT[db] = __builtin_amdgcn_mfma_f32_32x32x16_bf16(vf, pfrag[c], oT[db], 0, 0, 0);
                }
            __builtin_amdgcn_s_setprio(0);
        }

        asm volatile("s_waitcnt lgkmcnt(0)" ::: "memory");
        __builtin_amdgcn_sched_barrier(0);
        __builtin_amdgcn_s_barrier();
        __builtin_amdgcn_sched_barrier(0);
        p ^= 1;
    }

    // ---- epilogue: in-LDS combine of the two KV halves ----
    float lsum = l_lane + __shfl_xor(l_lane, 32);
    float* lsf = (float*)lsBuf;                    // [2][128][65] f32
    const int row = qg * 32 + ql;
#pragma unroll
    for (int db = 0; db < 2; ++db)
#pragma unroll
        for (int r = 0; r < 16; ++r) {
            int d = db * 32 + (r & 3) + 8 * (r >> 2) + 4 * h;
            lsf[(hf * 128 + row) * 65 + d] = oT[db][r];
        }
    if (h == 0) lsf[(hf * 128 + row) * 65 + 64] = lsum;
    __syncthreads();

    const int orow = t >> 2;                       // 0..127
    const int ck = t & 3;
    const float* e0 = lsf + orow * 65;
    const float* e1 = lsf + (128 + orow) * 65;
    const float linv = 1.0f / (e0[64] + e1[64]);
    const int b = bh >> 4, hh = bh & 15;
    const int d0 = ck * 16;
    unsigned short* op = o_ws + ((size_t)b * SS + qp * 128 + orow) * DM + hh * DKH + d0;
    uint4 o0, o1;
    o0.x = (unsigned)cvtpk((e0[d0+0]+e1[d0+0])*linv,  (e0[d0+1]+e1[d0+1])*linv);
    o0.y = (unsigned)cvtpk((e0[d0+2]+e1[d0+2])*linv,  (e0[d0+3]+e1[d0+3])*linv);
    o0.z = (unsigned)cvtpk((e0[d0+4]+e1[d0+4])*linv,  (e0[d0+5]+e1[d0+5])*linv);
    o0.w = (unsigned)cvtpk((e0[d0+6]+e1[d0+6])*linv,  (e0[d0+7]+e1[d0+7])*linv);
    o1.x = (unsigned)cvtpk((e0[d0+8]+e1[d0+8])*linv,  (e0[d0+9]+e1[d0+9])*linv);
    o1.y = (unsigned)cvtpk((e0[d0+10]+e1[d0+10])*linv,(e0[d0+11]+e1[d0+11])*linv);
    o1.z = (unsigned)cvtpk((e0[d0+12]+e1[d0+12])*linv,(e0[d0+13]+e1[d0+13])*linv);
    o1.w = (unsigned)cvtpk((e0[d0+14]+e1[d0+14])*linv,(e0[d0+15]+e1[d0+15])*linv);
    *(uint4*)op = o0;
    *(uint4*)(op + 8) = o1;
}

// ---------------- Output projection: 128x64 tile, 3-buffer counted-vmcnt pipeline ---------
__global__ __launch_bounds__(256) void proj_o_b(
    const unsigned short* __restrict__ A, const unsigned short* __restrict__ W,
    const float* __restrict__ bo, float* __restrict__ out)
{
    __shared__ unsigned short lA[3][128 * 32];
    __shared__ unsigned short lB[3][64 * 32];

    const int t = threadIdx.x;
    const int lane = t & 63, w = t >> 6;
    const int wm = w >> 1, wn = w & 1;
    const int g = lane >> 4, lr = lane & 15;

    const int hid = blockIdx.y * 16 + blockIdx.x;   // 512 blocks
    const int xcd = hid & 7, slot = hid >> 3;       // slot 0..63
    const int mbase = (xcd * 4 + (slot & 3)) * 128; // 32 M-panels
    const int nbase = (slot >> 2) * 64;             // 16 N-panels

    const int srow = lane >> 2;
    const int scol = (lane & 3) * 8;

    v4f acc[4][2];
#pragma unroll
    for (int i = 0; i < 4; ++i)
#pragma unroll
        for (int j = 0; j < 2; ++j)
            acc[i][j] = (v4f){0.f, 0.f, 0.f, 0.f};

    auto stage = [&](int bi, int kb) {   // 3 gl16 per wave
        gl16(A + (size_t)(mbase + w * 16 + srow) * DM + kb + scol,      &lA[bi][w * 512]);
        gl16(A + (size_t)(mbase + 64 + w * 16 + srow) * DM + kb + scol, &lA[bi][(w + 4) * 512]);
        gl16(W + (size_t)(nbase + w * 16 + srow) * DM + kb + scol,      &lB[bi][w * 512]);
    };
    auto compute = [&](int bi) {
        v8bf af[4], bf4[2];
#pragma unroll
        for (int mt = 0; mt < 4; ++mt)
            af[mt] = *(const v8bf*)(&lA[bi][(wm * 64 + mt * 16 + lr) * 32 + g * 8]);
#pragma unroll
        for (int nt = 0; nt < 2; ++nt)
            bf4[nt] = *(const v8bf*)(&lB[bi][(wn * 32 + nt * 16 + lr) * 32 + g * 8]);
#pragma unroll
        for (int mt = 0; mt < 4; ++mt)
#pragma unroll
            for (int nt = 0; nt < 2; ++nt)
                acc[mt][nt] = __builtin_amdgcn_mfma_f32_16x16x32_bf16(af[mt], bf4[nt], acc[mt][nt], 0, 0, 0);
    };

    stage(0, 0);
    stage(1, 32);
    int bcur = 0;
#pragma unroll 1
    for (int ki = 0; ki < 30; ++ki) {
        int bnext = bcur + 2; if (bnext >= 3) bnext -= 3;
        stage(bnext, (ki + 2) * 32);
        asm volatile("s_waitcnt vmcnt(6)" ::: "memory");
        __builtin_amdgcn_sched_barrier(0);
        __builtin_amdgcn_s_barrier();
        __builtin_amdgcn_sched_barrier(0);
        compute(bcur);
        __builtin_amdgcn_sched_barrier(0);
        __builtin_amdgcn_s_barrier();
        bcur = (bcur == 2) ? 0 : bcur + 1;
    }
    asm volatile("s_waitcnt vmcnt(3)" ::: "memory");
    __builtin_amdgcn_sched_barrier(0);
    __builtin_amdgcn_s_barrier();
    __builtin_amdgcn_sched_barrier(0);
    compute(bcur);
    __builtin_amdgcn_sched_barrier(0);
    __builtin_amdgcn_s_barrier();
    bcur = (bcur == 2) ? 0 : bcur + 1;
    asm volatile("s_waitcnt vmcnt(0)" ::: "memory");
    __builtin_amdgcn_sched_barrier(0);
    __builtin_amdgcn_s_barrier();
    __builtin_amdgcn_sched_barrier(0);
    compute(bcur);

#pragma unroll
    for (int nt = 0; nt < 2; ++nt) {
        int e = nbase + wn * 32 + nt * 16 + lr;
        float bval = bo[e];
#pragma unroll
        for (int mt = 0; mt < 4; ++mt) {
#pragma unroll
            for (int r = 0; r < 4; ++r) {
                int m = mbase + wm * 64 + mt * 16 + g * 4 + r;
                out[(size_t)m * DM + e] = acc[mt][nt][r] + bval;
            }
        }
    }
}

extern "C" void kernel_launch(void* const* d_in, const int* in_sizes, int n_in,
                              void* d_out, int out_size, void* d_ws, size_t ws_size,
                              hipStream_t stream) {
    const float* q  = (const float*)d_in[0];
    const float* k  = (const float*)d_in[1];
    const float* v  = (const float*)d_in[2];
    const float* wq = (const float*)d_in[3];
    const float* bq = (const float*)d_in[4];
    const float* wk = (const float*)d_in[5];
    const float* bk = (const float*)d_in[6];
    const float* wv = (const float*)d_in[7];
    const float* bv = (const float*)d_in[8];
    const float* wo = (const float*)d_in[9];
    const float* bo = (const float*)d_in[10];
    float* out = (float*)d_out;

    unsigned short* ws    = (unsigned short*)d_ws;
    unsigned short* q_ws  = ws;                                   // 8 MB
    unsigned short* k_ws  = q_ws + (size_t)MM * DM;               // 8 MB
    unsigned short* vt_ws = k_ws + (size_t)MM * DM;               // 8 MB
    unsigned short* xb    = vt_ws + (size_t)MM * DM;              // 24 MB  [xq|xk|xv]
    unsigned short* wb    = xb + (size_t)3 * MM * DM;             // 8 MB   [wq|wk|wv|wo]
    unsigned short* o_ws  = xb;   // alias: xb dead once proj completes

    cvt_to_bf16<<<dim3(256, 7), 256, 0, stream>>>(q, k, v, wq, wk, wv, wo, xb);
    proj_qkv_8p<<<dim3(8, 8, 3), 512, 0, stream>>>(xb, wb, bq, bk, bv, q_ws, k_ws, vt_ws);
    attn_kernel<<<dim3(512), 512, 0, stream>>>(q_ws, k_ws, vt_ws, o_ws);
    proj_o_b<<<dim3(16, 32), 256, 0, stream>>>(o_ws, wb + (size_t)3 * DM * DM, bo, out);
}

// Round 16
// 131.169 us; speedup vs baseline: 1.0575x; 1.0575x over previous
//
#include <hip/hip_runtime.h>
#include <hip/hip_bf16.h>

#define DM 1024
#define NH 16
#define DKH 64
#define BB 2
#define SS 2048
#define MM (BB*SS)   // 4096
#define HKB 1024     // KV half length

typedef __bf16 v8bf __attribute__((ext_vector_type(8)));
typedef float  v4f  __attribute__((ext_vector_type(4)));
typedef float  v16f __attribute__((ext_vector_type(16)));

__device__ __forceinline__ unsigned short f2bf(float f) {
    union { float f; unsigned int u; } v; v.f = f;
    unsigned int u = v.u;
    unsigned int r = (u + 0x7fffu + ((u >> 16) & 1u)) >> 16;
    return (unsigned short)r;
}

__device__ __forceinline__ int cvtpk(float lo, float hi) {
    int r;
    asm("v_cvt_pk_bf16_f32 %0, %1, %2" : "=v"(r) : "v"(lo), "v"(hi));
    return r;
}

__device__ __forceinline__ void pl32swap(int& a, int& b) {
    asm("v_permlane32_swap_b32 %0, %1" : "+v"(a), "+v"(b));
}

__device__ __forceinline__ void gl16(const void* g, void* l) {
    auto gp = reinterpret_cast<const __attribute__((address_space(1))) unsigned int*>(
        reinterpret_cast<uintptr_t>(g));
    auto lp = reinterpret_cast<__attribute__((address_space(3))) unsigned int*>(
        reinterpret_cast<uintptr_t>(l));
    __builtin_amdgcn_global_load_lds(gp, lp, 16, 0, 0);
}

// ---------------- fp32 -> bf16 one-shot convert: [xq|xk|xv] then [wq|wk|wv|wo] -----------
__global__ __launch_bounds__(256) void cvt_to_bf16(
    const float* __restrict__ xq, const float* __restrict__ xk, const float* __restrict__ xv,
    const float* __restrict__ wq, const float* __restrict__ wk, const float* __restrict__ wv,
    const float* __restrict__ wo, unsigned short* __restrict__ dst)
{
    const int y = blockIdx.y;
    const float* src;
    size_t n, off;
    if (y < 3) {
        src = (y == 0) ? xq : (y == 1) ? xk : xv;
        n = (size_t)MM * DM;
        off = (size_t)y * MM * DM;
    } else {
        src = (y == 3) ? wq : (y == 4) ? wk : (y == 5) ? wv : wo;
        n = (size_t)DM * DM;
        off = (size_t)3 * MM * DM + (size_t)(y - 3) * DM * DM;
    }
    unsigned short* d = dst + off;
    const size_t stride = (size_t)gridDim.x * blockDim.x;
    for (size_t i = (size_t)blockIdx.x * blockDim.x + threadIdx.x; i * 8 < n; i += stride) {
        float4 a = ((const float4*)src)[2 * i];
        float4 b = ((const float4*)src)[2 * i + 1];
        uint4 o;
        o.x = (unsigned)cvtpk(a.x, a.y);
        o.y = (unsigned)cvtpk(a.z, a.w);
        o.z = (unsigned)cvtpk(b.x, b.y);
        o.w = (unsigned)cvtpk(b.z, b.w);
        ((uint4*)d)[i] = o;
    }
}

// ---------------- QKV projection: 128x128 tile, 3-buffer counted-vmcnt pipeline (R8) -----
// z=0: Q (scaled by 0.125*log2e, layout [bh][s][64]); z=1: K; z=2: V^T ([bh][64][s])
__global__ __launch_bounds__(256) void proj_qkv_b(
    const unsigned short* __restrict__ xb, const unsigned short* __restrict__ wb,
    const float* __restrict__ bq, const float* __restrict__ bk, const float* __restrict__ bv,
    unsigned short* __restrict__ q_ws, unsigned short* __restrict__ k_ws,
    unsigned short* __restrict__ vt_ws)
{
    const int z = blockIdx.z;
    const unsigned short* X = xb + (size_t)z * MM * DM;
    const unsigned short* W = wb + (size_t)z * DM * DM;
    const float* bias = (z == 0) ? bq : (z == 1) ? bk : bv;

    __shared__ unsigned short lA[3][128 * 32];
    __shared__ unsigned short lB[3][128 * 32];

    const int t = threadIdx.x;
    const int lane = t & 63, w = t >> 6;
    const int wm = w >> 1, wn = w & 1;
    const int g = lane >> 4, lr = lane & 15;

    const int hid = blockIdx.y * 8 + blockIdx.x;
    const int xcd = hid & 7, slot = hid >> 3;
    const int mbase = (xcd * 4 + (slot & 3)) * 128;
    const int nbase = (slot >> 2) * 128;

    const int srow = lane >> 2;        // 0..15
    const int scol = (lane & 3) * 8;   // 0,8,16,24

    v4f acc[4][4];
#pragma unroll
    for (int i = 0; i < 4; ++i)
#pragma unroll
        for (int j = 0; j < 4; ++j)
            acc[i][j] = (v4f){0.f, 0.f, 0.f, 0.f};

    auto stage = [&](int bi, int kb) {   // 4 gl16 per wave
        gl16(X + (size_t)(mbase + w * 16 + srow) * DM + kb + scol,      &lA[bi][w * 512]);
        gl16(X + (size_t)(mbase + 64 + w * 16 + srow) * DM + kb + scol, &lA[bi][(w + 4) * 512]);
        gl16(W + (size_t)(nbase + w * 16 + srow) * DM + kb + scol,      &lB[bi][w * 512]);
        gl16(W + (size_t)(nbase + 64 + w * 16 + srow) * DM + kb + scol, &lB[bi][(w + 4) * 512]);
    };
    auto compute = [&](int bi) {
        v8bf af[4], bf4[4];
#pragma unroll
        for (int mt = 0; mt < 4; ++mt)
            af[mt] = *(const v8bf*)(&lA[bi][(wm * 64 + mt * 16 + lr) * 32 + g * 8]);
#pragma unroll
        for (int nt = 0; nt < 4; ++nt)
            bf4[nt] = *(const v8bf*)(&lB[bi][(wn * 64 + nt * 16 + lr) * 32 + g * 8]);
#pragma unroll
        for (int mt = 0; mt < 4; ++mt)
#pragma unroll
            for (int nt = 0; nt < 4; ++nt)
                acc[mt][nt] = __builtin_amdgcn_mfma_f32_16x16x32_bf16(af[mt], bf4[nt], acc[mt][nt], 0, 0, 0);
    };

    stage(0, 0);
    stage(1, 32);
    int bcur = 0;
#pragma unroll 1
    for (int ki = 0; ki < 30; ++ki) {
        int bnext = bcur + 2; if (bnext >= 3) bnext -= 3;
        stage(bnext, (ki + 2) * 32);
        asm volatile("s_waitcnt vmcnt(8)" ::: "memory");   // keep 2 stages in flight
        __builtin_amdgcn_sched_barrier(0);
        __builtin_amdgcn_s_barrier();
        __builtin_amdgcn_sched_barrier(0);
        compute(bcur);
        __builtin_amdgcn_sched_barrier(0);
        __builtin_amdgcn_s_barrier();
        bcur = (bcur == 2) ? 0 : bcur + 1;
    }
    asm volatile("s_waitcnt vmcnt(4)" ::: "memory");       // ki=30
    __builtin_amdgcn_sched_barrier(0);
    __builtin_amdgcn_s_barrier();
    __builtin_amdgcn_sched_barrier(0);
    compute(bcur);
    __builtin_amdgcn_sched_barrier(0);
    __builtin_amdgcn_s_barrier();
    bcur = (bcur == 2) ? 0 : bcur + 1;
    asm volatile("s_waitcnt vmcnt(0)" ::: "memory");       // ki=31
    __builtin_amdgcn_sched_barrier(0);
    __builtin_amdgcn_s_barrier();
    __builtin_amdgcn_sched_barrier(0);
    compute(bcur);

    const float scale = (z == 0) ? 0.18033688011112042f : 1.0f;  // 0.125*log2(e) for Q
#pragma unroll
    for (int nt = 0; nt < 4; ++nt) {
        int e = nbase + wn * 64 + nt * 16 + lr;
        float bval = bias[e];
        int h = e >> 6, dk = e & 63;
#pragma unroll
        for (int mt = 0; mt < 4; ++mt) {
#pragma unroll
            for (int r = 0; r < 4; ++r) {
                int m = mbase + wm * 64 + mt * 16 + g * 4 + r;
                float val = (acc[mt][nt][r] + bval) * scale;
                unsigned short o = f2bf(val);
                int b = m >> 11, s = m & 2047;
                if (z == 2) {
                    vt_ws[((size_t)(b * NH + h) * DKH + dk) * SS + s] = o;
                } else {
                    unsigned short* dst = (z == 0) ? q_ws : k_ws;
                    dst[((size_t)(b * NH + h) * SS + s) * DKH + dk] = o;
                }
            }
        }
    }
}

// ------- Flash attention v7: gl16 KV staging, XOR-chunk swizzle, depth-1 double buffer ----
// LDS layout per buffer: 4 linear tiles [K0|V0|K1|V1], each [64 rows][64 elems],
// with LDS[row][ch] = src[row][ch ^ (row&7)] (pre-swizzled global source chunk).
#define KB 64
#define ATILE 4096                 // shorts per 64x64 tile
#define ABUF  16384                // shorts per buffer (4 tiles)

__global__ __launch_bounds__(512, 2) void attn_kernel(
    const unsigned short* __restrict__ q_ws, const unsigned short* __restrict__ k_ws,
    const unsigned short* __restrict__ vt_ws, unsigned short* __restrict__ o_ws)
{
    __shared__ __align__(16) unsigned short ls[33280];   // 66560 B (2 bufs / f32 epilogue)

    const int t = threadIdx.x, l = t & 63, w = t >> 6;   // w 0..7
    const int h = l >> 5, ql = l & 31;
    const int qg = w >> 1, hf = w & 1;

    const int hid = blockIdx.x;
    const int slot = hid >> 3;
    const int bh = (hid & 7) * 4 + (slot & 3);
    const int qp = slot >> 2;              // 0..15, 128 q rows each
    const int q0 = qp * 128 + qg * 32;

    const unsigned short* Kb = k_ws + (size_t)bh * SS * DKH;
    const unsigned short* Vb = vt_ws + (size_t)bh * DKH * SS;

    v8bf qf[4];
#pragma unroll
    for (int c = 0; c < 4; ++c)
        qf[c] = *(const v8bf*)(q_ws + ((size_t)bh * SS + q0 + ql) * DKH + c * 16 + h * 8);

    v16f oT[2];
#pragma unroll
    for (int d = 0; d < 2; ++d)
#pragma unroll
        for (int r = 0; r < 16; ++r) oT[d][r] = 0.f;
    float l_lane = 0.f;
    const v16f z16 = {};

    // stage KV tile-set at key offset kt into buffer bp: wave w covers 64-chunk groups
    // g64 = w*4+i; chunk j = g64*64 + lane; tile = g64>>3; row = (j&511)>>3; ch = j&7.
    auto stageKV = [&](int bp, int kt) {
#pragma unroll
        for (int i = 0; i < 4; ++i) {
            const int g64 = w * 4 + i;
            const int tile = g64 >> 3;           // wave-uniform
            const int jj = (g64 & 7) * 64 + l;   // chunk index within tile (0..511)
            const int row = jj >> 3;
            const int sch = (jj & 7) ^ (row & 7);
            const unsigned short* src;
            if (tile == 0)      src = Kb + (size_t)(kt + row) * DKH + sch * 8;
            else if (tile == 1) src = Vb + (size_t)row * SS + kt + sch * 8;
            else if (tile == 2) src = Kb + (size_t)(HKB + kt + row) * DKH + sch * 8;
            else                src = Vb + (size_t)row * SS + HKB + kt + sch * 8;
            gl16(src, &ls[bp * ABUF + g64 * 512]);
        }
    };

    stageKV(0, 0);
    asm volatile("s_waitcnt vmcnt(0)" ::: "memory");
    __builtin_amdgcn_sched_barrier(0);
    __builtin_amdgcn_s_barrier();
    __builtin_amdgcn_sched_barrier(0);

    const int NT = 16;
    int p = 0;
    for (int tt = 0; tt < NT; ++tt) {
        if (tt + 1 < NT) stageKV(p ^ 1, (tt + 1) * KB);   // direct-to-LDS, flies over compute

        const unsigned short* Kp = &ls[p * ABUF + (hf * 2) * ATILE];
        const unsigned short* Vp = Kp + ATILE;

        // ---- S^T = K . Q^T (zero-C first MFMA) ----
        v16f sT[2];
        __builtin_amdgcn_s_setprio(1);
#pragma unroll
        for (int kb = 0; kb < 2; ++kb) {
            int row = kb * 32 + ql;
            v8bf kf = *(const v8bf*)&Kp[row * 64 + ((h ^ (row & 7)) * 8)];
            sT[kb] = __builtin_amdgcn_mfma_f32_32x32x16_bf16(kf, qf[0], z16, 0, 0, 0);
        }
#pragma unroll
        for (int c = 1; c < 4; ++c)
#pragma unroll
            for (int kb = 0; kb < 2; ++kb) {
                int row = kb * 32 + ql;
                v8bf kf = *(const v8bf*)&Kp[row * 64 + (((c * 2 + h) ^ (row & 7)) * 8)];
                sT[kb] = __builtin_amdgcn_mfma_f32_32x32x16_bf16(kf, qf[c], sT[kb], 0, 0, 0);
            }
        __builtin_amdgcn_s_setprio(0);

        // ---- sm-split: per-kb {exp -> pack -> PV} ----
        v8bf pfrag[4];
#pragma unroll
        for (int kb = 0; kb < 2; ++kb) {
            float rs0 = 0.f, rs1 = 0.f, rs2 = 0.f, rs3 = 0.f;
#pragma unroll
            for (int r = 0; r < 16; r += 4) {
                float e0 = __builtin_amdgcn_exp2f(sT[kb][r + 0]);
                float e1 = __builtin_amdgcn_exp2f(sT[kb][r + 1]);
                float e2 = __builtin_amdgcn_exp2f(sT[kb][r + 2]);
                float e3 = __builtin_amdgcn_exp2f(sT[kb][r + 3]);
                sT[kb][r + 0] = e0; sT[kb][r + 1] = e1;
                sT[kb][r + 2] = e2; sT[kb][r + 3] = e3;
                rs0 += e0; rs1 += e1; rs2 += e2; rs3 += e3;
            }
            l_lane += (rs0 + rs1) + (rs2 + rs3);

#pragma unroll
            for (int cc = 0; cc < 2; ++cc) {
                int A0 = cvtpk(sT[kb][8 * cc + 0], sT[kb][8 * cc + 1]);
                int A1 = cvtpk(sT[kb][8 * cc + 2], sT[kb][8 * cc + 3]);
                int B0 = cvtpk(sT[kb][8 * cc + 4], sT[kb][8 * cc + 5]);
                int B1 = cvtpk(sT[kb][8 * cc + 6], sT[kb][8 * cc + 7]);
                pl32swap(A0, B0);
                pl32swap(A1, B1);
                union { int i[4]; v8bf v; } u;
                u.i[0] = A0; u.i[1] = A1; u.i[2] = B0; u.i[3] = B1;
                pfrag[kb * 2 + cc] = u.v;
            }

            __builtin_amdgcn_s_setprio(1);
#pragma unroll
            for (int db = 0; db < 2; ++db)
#pragma unroll
                for (int cc = 0; cc < 2; ++cc) {
                    int c = kb * 2 + cc;
                    int row = db * 32 + ql;
                    v8bf vf = *(const v8bf*)&Vp[row * 64 + (((c * 2 + h) ^ (row & 7)) * 8)];
                    oT[db] = __builtin_amdgcn_mfma_f32_32x32x16_bf16(vf, pfrag[c], oT[db], 0, 0, 0);
                }
            __builtin_amdgcn_s_setprio(0);
        }

        asm volatile("s_waitcnt vmcnt(0)" ::: "memory");   // next tile's gl16 landed
        __builtin_amdgcn_sched_barrier(0);
        __builtin_amdgcn_s_barrier();
        __builtin_amdgcn_sched_barrier(0);
        p ^= 1;
    }

    // ---- epilogue: in-LDS combine of the two KV halves ----
    float lsum = l_lane + __shfl_xor(l_lane, 32);
    float* lsf = (float*)ls;                       // [2][128][65] f32 = 66560 B
    const int row = qg * 32 + ql;
#pragma unroll
    for (int db = 0; db < 2; ++db)
#pragma unroll
        for (int r = 0; r < 16; ++r) {
            int d = db * 32 + (r & 3) + 8 * (r >> 2) + 4 * h;
            lsf[(hf * 128 + row) * 65 + d] = oT[db][r];
        }
    if (h == 0) lsf[(hf * 128 + row) * 65 + 64] = lsum;
    __syncthreads();

    const int orow = t >> 2;                       // 0..127
    const int ck = t & 3;
    const float* e0 = lsf + orow * 65;
    const float* e1 = lsf + (128 + orow) * 65;
    const float linv = 1.0f / (e0[64] + e1[64]);
    const int b = bh >> 4, hh = bh & 15;
    const int d0 = ck * 16;
    unsigned short* op = o_ws + ((size_t)b * SS + qp * 128 + orow) * DM + hh * DKH + d0;
    uint4 o0, o1;
    o0.x = (unsigned)cvtpk((e0[d0+0]+e1[d0+0])*linv,  (e0[d0+1]+e1[d0+1])*linv);
    o0.y = (unsigned)cvtpk((e0[d0+2]+e1[d0+2])*linv,  (e0[d0+3]+e1[d0+3])*linv);
    o0.z = (unsigned)cvtpk((e0[d0+4]+e1[d0+4])*linv,  (e0[d0+5]+e1[d0+5])*linv);
    o0.w = (unsigned)cvtpk((e0[d0+6]+e1[d0+6])*linv,  (e0[d0+7]+e1[d0+7])*linv);
    o1.x = (unsigned)cvtpk((e0[d0+8]+e1[d0+8])*linv,  (e0[d0+9]+e1[d0+9])*linv);
    o1.y = (unsigned)cvtpk((e0[d0+10]+e1[d0+10])*linv,(e0[d0+11]+e1[d0+11])*linv);
    o1.z = (unsigned)cvtpk((e0[d0+12]+e1[d0+12])*linv,(e0[d0+13]+e1[d0+13])*linv);
    o1.w = (unsigned)cvtpk((e0[d0+14]+e1[d0+14])*linv,(e0[d0+15]+e1[d0+15])*linv);
    *(uint4*)op = o0;
    *(uint4*)(op + 8) = o1;
}

// ---------------- Output projection: 128x64 tile, 3-buffer counted-vmcnt pipeline ---------
__global__ __launch_bounds__(256) void proj_o_b(
    const unsigned short* __restrict__ A, const unsigned short* __restrict__ W,
    const float* __restrict__ bo, float* __restrict__ out)
{
    __shared__ unsigned short lA[3][128 * 32];
    __shared__ unsigned short lB[3][64 * 32];

    const int t = threadIdx.x;
    const int lane = t & 63, w = t >> 6;
    const int wm = w >> 1, wn = w & 1;
    const int g = lane >> 4, lr = lane & 15;

    const int hid = blockIdx.y * 16 + blockIdx.x;   // 512 blocks
    const int xcd = hid & 7, slot = hid >> 3;       // slot 0..63
    const int mbase = (xcd * 4 + (slot & 3)) * 128; // 32 M-panels
    const int nbase = (slot >> 2) * 64;             // 16 N-panels

    const int srow = lane >> 2;
    const int scol = (lane & 3) * 8;

    v4f acc[4][2];
#pragma unroll
    for (int i = 0; i < 4; ++i)
#pragma unroll
        for (int j = 0; j < 2; ++j)
            acc[i][j] = (v4f){0.f, 0.f, 0.f, 0.f};

    auto stage = [&](int bi, int kb) {   // 3 gl16 per wave
        gl16(A + (size_t)(mbase + w * 16 + srow) * DM + kb + scol,      &lA[bi][w * 512]);
        gl16(A + (size_t)(mbase + 64 + w * 16 + srow) * DM + kb + scol, &lA[bi][(w + 4) * 512]);
        gl16(W + (size_t)(nbase + w * 16 + srow) * DM + kb + scol,      &lB[bi][w * 512]);
    };
    auto compute = [&](int bi) {
        v8bf af[4], bf4[2];
#pragma unroll
        for (int mt = 0; mt < 4; ++mt)
            af[mt] = *(const v8bf*)(&lA[bi][(wm * 64 + mt * 16 + lr) * 32 + g * 8]);
#pragma unroll
        for (int nt = 0; nt < 2; ++nt)
            bf4[nt] = *(const v8bf*)(&lB[bi][(wn * 32 + nt * 16 + lr) * 32 + g * 8]);
#pragma unroll
        for (int mt = 0; mt < 4; ++mt)
#pragma unroll
            for (int nt = 0; nt < 2; ++nt)
                acc[mt][nt] = __builtin_amdgcn_mfma_f32_16x16x32_bf16(af[mt], bf4[nt], acc[mt][nt], 0, 0, 0);
    };

    stage(0, 0);
    stage(1, 32);
    int bcur = 0;
#pragma unroll 1
    for (int ki = 0; ki < 30; ++ki) {
        int bnext = bcur + 2; if (bnext >= 3) bnext -= 3;
        stage(bnext, (ki + 2) * 32);
        asm volatile("s_waitcnt vmcnt(6)" ::: "memory");
        __builtin_amdgcn_sched_barrier(0);
        __builtin_amdgcn_s_barrier();
        __builtin_amdgcn_sched_barrier(0);
        compute(bcur);
        __builtin_amdgcn_sched_barrier(0);
        __builtin_amdgcn_s_barrier();
        bcur = (bcur == 2) ? 0 : bcur + 1;
    }
    asm volatile("s_waitcnt vmcnt(3)" ::: "memory");
    __builtin_amdgcn_sched_barrier(0);
    __builtin_amdgcn_s_barrier();
    __builtin_amdgcn_sched_barrier(0);
    compute(bcur);
    __builtin_amdgcn_sched_barrier(0);
    __builtin_amdgcn_s_barrier();
    bcur = (bcur == 2) ? 0 : bcur + 1;
    asm volatile("s_waitcnt vmcnt(0)" ::: "memory");
    __builtin_amdgcn_sched_barrier(0);
    __builtin_amdgcn_s_barrier();
    __builtin_amdgcn_sched_barrier(0);
    compute(bcur);

#pragma unroll
    for (int nt = 0; nt < 2; ++nt) {
        int e = nbase + wn * 32 + nt * 16 + lr;
        float bval = bo[e];
#pragma unroll
        for (int mt = 0; mt < 4; ++mt) {
#pragma unroll
            for (int r = 0; r < 4; ++r) {
                int m = mbase + wm * 64 + mt * 16 + g * 4 + r;
                out[(size_t)m * DM + e] = acc[mt][nt][r] + bval;
            }
        }
    }
}

extern "C" void kernel_launch(void* const* d_in, const int* in_sizes, int n_in,
                              void* d_out, int out_size, void* d_ws, size_t ws_size,
                              hipStream_t stream) {
    const float* q  = (const float*)d_in[0];
    const float* k  = (const float*)d_in[1];
    const float* v  = (const float*)d_in[2];
    const float* wq = (const float*)d_in[3];
    const float* bq = (const float*)d_in[4];
    const float* wk = (const float*)d_in[5];
    const float* bk = (const float*)d_in[6];
    const float* wv = (const float*)d_in[7];
    const float* bv = (const float*)d_in[8];
    const float* wo = (const float*)d_in[9];
    const float* bo = (const float*)d_in[10];
    float* out = (float*)d_out;

    unsigned short* ws    = (unsigned short*)d_ws;
    unsigned short* q_ws  = ws;                                   // 8 MB
    unsigned short* k_ws  = q_ws + (size_t)MM * DM;               // 8 MB
    unsigned short* vt_ws = k_ws + (size_t)MM * DM;               // 8 MB
    unsigned short* xb    = vt_ws + (size_t)MM * DM;              // 24 MB  [xq|xk|xv]
    unsigned short* wb    = xb + (size_t)3 * MM * DM;             // 8 MB   [wq|wk|wv|wo]
    unsigned short* o_ws  = xb;   // alias: xb dead once proj_qkv_b completes

    cvt_to_bf16<<<dim3(256, 7), 256, 0, stream>>>(q, k, v, wq, wk, wv, wo, xb);
    proj_qkv_b<<<dim3(8, 32, 3), 256, 0, stream>>>(xb, wb, bq, bk, bv, q_ws, k_ws, vt_ws);
    attn_kernel<<<dim3(512), 512, 0, stream>>>(q_ws, k_ws, vt_ws, o_ws);
    proj_o_b<<<dim3(16, 32), 256, 0, stream>>>(o_ws, wb + (size_t)3 * DM * DM, bo, out);
}

// Round 17
// 120.316 us; speedup vs baseline: 1.1529x; 1.0902x over previous
//
#include <hip/hip_runtime.h>
#include <hip/hip_bf16.h>

#define DM 1024
#define NH 16
#define DKH 64
#define BB 2
#define SS 2048
#define MM (BB*SS)   // 4096
#define HKB 1024     // KV half length

typedef __bf16 v8bf __attribute__((ext_vector_type(8)));
typedef float  v4f  __attribute__((ext_vector_type(4)));
typedef float  v16f __attribute__((ext_vector_type(16)));

__device__ __forceinline__ unsigned short f2bf(float f) {
    union { float f; unsigned int u; } v; v.f = f;
    unsigned int u = v.u;
    unsigned int r = (u + 0x7fffu + ((u >> 16) & 1u)) >> 16;
    return (unsigned short)r;
}

__device__ __forceinline__ int cvtpk(float lo, float hi) {
    int r;
    asm("v_cvt_pk_bf16_f32 %0, %1, %2" : "=v"(r) : "v"(lo), "v"(hi));
    return r;
}

__device__ __forceinline__ void pl32swap(int& a, int& b) {
    asm("v_permlane32_swap_b32 %0, %1" : "+v"(a), "+v"(b));
}

__device__ __forceinline__ void gl16(const void* g, void* l) {
    auto gp = reinterpret_cast<const __attribute__((address_space(1))) unsigned int*>(
        reinterpret_cast<uintptr_t>(g));
    auto lp = reinterpret_cast<__attribute__((address_space(3))) unsigned int*>(
        reinterpret_cast<uintptr_t>(l));
    __builtin_amdgcn_global_load_lds(gp, lp, 16, 0, 0);
}

// ---------------- fp32 -> bf16 one-shot convert: [xq|xk|xv] then [wq|wk|wv|wo] -----------
__global__ __launch_bounds__(256) void cvt_to_bf16(
    const float* __restrict__ xq, const float* __restrict__ xk, const float* __restrict__ xv,
    const float* __restrict__ wq, const float* __restrict__ wk, const float* __restrict__ wv,
    const float* __restrict__ wo, unsigned short* __restrict__ dst)
{
    const int y = blockIdx.y;
    const float* src;
    size_t n, off;
    if (y < 3) {
        src = (y == 0) ? xq : (y == 1) ? xk : xv;
        n = (size_t)MM * DM;
        off = (size_t)y * MM * DM;
    } else {
        src = (y == 3) ? wq : (y == 4) ? wk : (y == 5) ? wv : wo;
        n = (size_t)DM * DM;
        off = (size_t)3 * MM * DM + (size_t)(y - 3) * DM * DM;
    }
    unsigned short* d = dst + off;
    const size_t stride = (size_t)gridDim.x * blockDim.x;
    for (size_t i = (size_t)blockIdx.x * blockDim.x + threadIdx.x; i * 8 < n; i += stride) {
        float4 a = ((const float4*)src)[2 * i];
        float4 b = ((const float4*)src)[2 * i + 1];
        uint4 o;
        o.x = (unsigned)cvtpk(a.x, a.y);
        o.y = (unsigned)cvtpk(a.z, a.w);
        o.z = (unsigned)cvtpk(b.x, b.y);
        o.w = (unsigned)cvtpk(b.z, b.w);
        ((uint4*)d)[i] = o;
    }
}

// ---------------- QKV projection: 128x128 tile, 3-buffer counted-vmcnt pipeline (R8) -----
// z=0: Q (scaled by 0.125*log2e, layout [bh][s][64]); z=1: K; z=2: V^T ([bh][64][s])
__global__ __launch_bounds__(256) void proj_qkv_b(
    const unsigned short* __restrict__ xb, const unsigned short* __restrict__ wb,
    const float* __restrict__ bq, const float* __restrict__ bk, const float* __restrict__ bv,
    unsigned short* __restrict__ q_ws, unsigned short* __restrict__ k_ws,
    unsigned short* __restrict__ vt_ws)
{
    const int z = blockIdx.z;
    const unsigned short* X = xb + (size_t)z * MM * DM;
    const unsigned short* W = wb + (size_t)z * DM * DM;
    const float* bias = (z == 0) ? bq : (z == 1) ? bk : bv;

    __shared__ unsigned short lA[3][128 * 32];
    __shared__ unsigned short lB[3][128 * 32];

    const int t = threadIdx.x;
    const int lane = t & 63, w = t >> 6;
    const int wm = w >> 1, wn = w & 1;
    const int g = lane >> 4, lr = lane & 15;

    const int hid = blockIdx.y * 8 + blockIdx.x;
    const int xcd = hid & 7, slot = hid >> 3;
    const int mbase = (xcd * 4 + (slot & 3)) * 128;
    const int nbase = (slot >> 2) * 128;

    const int srow = lane >> 2;        // 0..15
    const int scol = (lane & 3) * 8;   // 0,8,16,24

    v4f acc[4][4];
#pragma unroll
    for (int i = 0; i < 4; ++i)
#pragma unroll
        for (int j = 0; j < 4; ++j)
            acc[i][j] = (v4f){0.f, 0.f, 0.f, 0.f};

    auto stage = [&](int bi, int kb) {   // 4 gl16 per wave
        gl16(X + (size_t)(mbase + w * 16 + srow) * DM + kb + scol,      &lA[bi][w * 512]);
        gl16(X + (size_t)(mbase + 64 + w * 16 + srow) * DM + kb + scol, &lA[bi][(w + 4) * 512]);
        gl16(W + (size_t)(nbase + w * 16 + srow) * DM + kb + scol,      &lB[bi][w * 512]);
        gl16(W + (size_t)(nbase + 64 + w * 16 + srow) * DM + kb + scol, &lB[bi][(w + 4) * 512]);
    };
    auto compute = [&](int bi) {
        v8bf af[4], bf4[4];
#pragma unroll
        for (int mt = 0; mt < 4; ++mt)
            af[mt] = *(const v8bf*)(&lA[bi][(wm * 64 + mt * 16 + lr) * 32 + g * 8]);
#pragma unroll
        for (int nt = 0; nt < 4; ++nt)
            bf4[nt] = *(const v8bf*)(&lB[bi][(wn * 64 + nt * 16 + lr) * 32 + g * 8]);
#pragma unroll
        for (int mt = 0; mt < 4; ++mt)
#pragma unroll
            for (int nt = 0; nt < 4; ++nt)
                acc[mt][nt] = __builtin_amdgcn_mfma_f32_16x16x32_bf16(af[mt], bf4[nt], acc[mt][nt], 0, 0, 0);
    };

    stage(0, 0);
    stage(1, 32);
    int bcur = 0;
#pragma unroll 1
    for (int ki = 0; ki < 30; ++ki) {
        int bnext = bcur + 2; if (bnext >= 3) bnext -= 3;
        stage(bnext, (ki + 2) * 32);
        asm volatile("s_waitcnt vmcnt(8)" ::: "memory");   // keep 2 stages in flight
        __builtin_amdgcn_sched_barrier(0);
        __builtin_amdgcn_s_barrier();
        __builtin_amdgcn_sched_barrier(0);
        compute(bcur);
        __builtin_amdgcn_sched_barrier(0);
        __builtin_amdgcn_s_barrier();
        bcur = (bcur == 2) ? 0 : bcur + 1;
    }
    asm volatile("s_waitcnt vmcnt(4)" ::: "memory");       // ki=30
    __builtin_amdgcn_sched_barrier(0);
    __builtin_amdgcn_s_barrier();
    __builtin_amdgcn_sched_barrier(0);
    compute(bcur);
    __builtin_amdgcn_sched_barrier(0);
    __builtin_amdgcn_s_barrier();
    bcur = (bcur == 2) ? 0 : bcur + 1;
    asm volatile("s_waitcnt vmcnt(0)" ::: "memory");       // ki=31
    __builtin_amdgcn_sched_barrier(0);
    __builtin_amdgcn_s_barrier();
    __builtin_amdgcn_sched_barrier(0);
    compute(bcur);

    const float scale = (z == 0) ? 0.18033688011112042f : 1.0f;  // 0.125*log2(e) for Q
#pragma unroll
    for (int nt = 0; nt < 4; ++nt) {
        int e = nbase + wn * 64 + nt * 16 + lr;
        float bval = bias[e];
        int h = e >> 6, dk = e & 63;
#pragma unroll
        for (int mt = 0; mt < 4; ++mt) {
#pragma unroll
            for (int r = 0; r < 4; ++r) {
                int m = mbase + wm * 64 + mt * 16 + g * 4 + r;
                float val = (acc[mt][nt][r] + bval) * scale;
                unsigned short o = f2bf(val);
                int b = m >> 11, s = m & 2047;
                if (z == 2) {
                    vt_ws[((size_t)(b * NH + h) * DKH + dk) * SS + s] = o;
                } else {
                    unsigned short* dst = (z == 0) ? q_ws : k_ws;
                    dst[((size_t)(b * NH + h) * SS + s) * DKH + dk] = o;
                }
            }
        }
    }
}

// ------------- Flash attention v6: sm-split per kb (exp/pack kb1 overlaps PV kb0) ---------
#define KB 64
#define LDP 72
#define TILE 4608   // shorts per 64x64 tile with pad

__global__ __launch_bounds__(512, 4) void attn_kernel(
    const unsigned short* __restrict__ q_ws, const unsigned short* __restrict__ k_ws,
    const unsigned short* __restrict__ vt_ws, unsigned short* __restrict__ o_ws)
{
    __shared__ __align__(16) unsigned short lsBuf[2 * 4 * TILE];   // 73728 B

    const int t = threadIdx.x, l = t & 63, w = t >> 6;   // w 0..7
    const int h = l >> 5, ql = l & 31;
    const int qg = w >> 1, hf = w & 1;

    const int hid = blockIdx.x;
    const int slot = hid >> 3;
    const int bh = (hid & 7) * 4 + (slot & 3);
    const int qp = slot >> 2;              // 0..15, 128 q rows each
    const int q0 = qp * 128 + qg * 32;

    const unsigned short* Kb = k_ws + (size_t)bh * SS * DKH;
    const unsigned short* Vb = vt_ws + (size_t)bh * DKH * SS;

    v8bf qf[4];
#pragma unroll
    for (int c = 0; c < 4; ++c)
        qf[c] = *(const v8bf*)(q_ws + ((size_t)bh * SS + q0 + ql) * DKH + c * 16 + h * 8);

    v16f oT[2];
#pragma unroll
    for (int d = 0; d < 2; ++d)
#pragma unroll
        for (int r = 0; r < 16; ++r) oT[d][r] = 0.f;
    float l_lane = 0.f;
    const v16f z16 = {};

    const int r0s = t >> 3, c0s = (t & 7) * 8;
    uint4 k0r, k1r, v0r, v1r;

    k0r = *(const uint4*)(Kb + (size_t)(r0s) * DKH + c0s);
    v0r = *(const uint4*)(Vb + (size_t)r0s * SS + c0s);
    k1r = *(const uint4*)(Kb + (size_t)(HKB + r0s) * DKH + c0s);
    v1r = *(const uint4*)(Vb + (size_t)r0s * SS + HKB + c0s);
    {
        unsigned short* B0 = lsBuf;
        *(uint4*)&B0[0 * TILE + r0s * LDP + c0s] = k0r;
        *(uint4*)&B0[1 * TILE + r0s * LDP + c0s] = v0r;
        *(uint4*)&B0[2 * TILE + r0s * LDP + c0s] = k1r;
        *(uint4*)&B0[3 * TILE + r0s * LDP + c0s] = v1r;
    }
    k0r = *(const uint4*)(Kb + (size_t)(KB + r0s) * DKH + c0s);
    v0r = *(const uint4*)(Vb + (size_t)r0s * SS + KB + c0s);
    k1r = *(const uint4*)(Kb + (size_t)(HKB + KB + r0s) * DKH + c0s);
    v1r = *(const uint4*)(Vb + (size_t)r0s * SS + HKB + KB + c0s);
    asm volatile("s_waitcnt lgkmcnt(0)" ::: "memory");
    __builtin_amdgcn_sched_barrier(0);
    __builtin_amdgcn_s_barrier();
    __builtin_amdgcn_sched_barrier(0);

    const int NT = 16;
    int p = 0;
    for (int tt = 0; tt < NT; ++tt) {
        unsigned short* Kp = lsBuf + p * (4 * TILE) + hf * (2 * TILE);
        unsigned short* Vp = Kp + TILE;
        if (tt + 1 < NT) {
            unsigned short* Bn = lsBuf + (p ^ 1) * (4 * TILE);
            *(uint4*)&Bn[0 * TILE + r0s * LDP + c0s] = k0r;
            *(uint4*)&Bn[1 * TILE + r0s * LDP + c0s] = v0r;
            *(uint4*)&Bn[2 * TILE + r0s * LDP + c0s] = k1r;
            *(uint4*)&Bn[3 * TILE + r0s * LDP + c0s] = v1r;
        }
        if (tt + 2 < NT) {
            int kt2 = (tt + 2) * KB;
            k0r = *(const uint4*)(Kb + (size_t)(kt2 + r0s) * DKH + c0s);
            v0r = *(const uint4*)(Vb + (size_t)r0s * SS + kt2 + c0s);
            k1r = *(const uint4*)(Kb + (size_t)(HKB + kt2 + r0s) * DKH + c0s);
            v1r = *(const uint4*)(Vb + (size_t)r0s * SS + HKB + kt2 + c0s);
        }

        // ---- S^T = K . Q^T (zero-C first MFMA) ----
        v16f sT[2];
        __builtin_amdgcn_s_setprio(1);
#pragma unroll
        for (int kb = 0; kb < 2; ++kb) {
            v8bf kf = *(const v8bf*)&Kp[(kb * 32 + ql) * LDP + h * 8];
            sT[kb] = __builtin_amdgcn_mfma_f32_32x32x16_bf16(kf, qf[0], z16, 0, 0, 0);
        }
#pragma unroll
        for (int c = 1; c < 4; ++c)
#pragma unroll
            for (int kb = 0; kb < 2; ++kb) {
                v8bf kf = *(const v8bf*)&Kp[(kb * 32 + ql) * LDP + c * 16 + h * 8];
                sT[kb] = __builtin_amdgcn_mfma_f32_32x32x16_bf16(kf, qf[c], sT[kb], 0, 0, 0);
            }
        __builtin_amdgcn_s_setprio(0);

        // ---- sm-split: per-kb {exp -> pack -> PV} so kb1's VALU overlaps PV kb0 ----
        v8bf pfrag[4];
#pragma unroll
        for (int kb = 0; kb < 2; ++kb) {
            float rs0 = 0.f, rs1 = 0.f, rs2 = 0.f, rs3 = 0.f;
#pragma unroll
            for (int r = 0; r < 16; r += 4) {
                float e0 = __builtin_amdgcn_exp2f(sT[kb][r + 0]);
                float e1 = __builtin_amdgcn_exp2f(sT[kb][r + 1]);
                float e2 = __builtin_amdgcn_exp2f(sT[kb][r + 2]);
                float e3 = __builtin_amdgcn_exp2f(sT[kb][r + 3]);
                sT[kb][r + 0] = e0; sT[kb][r + 1] = e1;
                sT[kb][r + 2] = e2; sT[kb][r + 3] = e3;
                rs0 += e0; rs1 += e1; rs2 += e2; rs3 += e3;
            }
            l_lane += (rs0 + rs1) + (rs2 + rs3);

#pragma unroll
            for (int cc = 0; cc < 2; ++cc) {
                int A0 = cvtpk(sT[kb][8 * cc + 0], sT[kb][8 * cc + 1]);
                int A1 = cvtpk(sT[kb][8 * cc + 2], sT[kb][8 * cc + 3]);
                int B0 = cvtpk(sT[kb][8 * cc + 4], sT[kb][8 * cc + 5]);
                int B1 = cvtpk(sT[kb][8 * cc + 6], sT[kb][8 * cc + 7]);
                pl32swap(A0, B0);
                pl32swap(A1, B1);
                union { int i[4]; v8bf v; } u;
                u.i[0] = A0; u.i[1] = A1; u.i[2] = B0; u.i[3] = B1;
                pfrag[kb * 2 + cc] = u.v;
            }

            __builtin_amdgcn_s_setprio(1);
#pragma unroll
            for (int db = 0; db < 2; ++db)
#pragma unroll
                for (int cc = 0; cc < 2; ++cc) {
                    int c = kb * 2 + cc;
                    v8bf vf = *(const v8bf*)&Vp[(db * 32 + ql) * LDP + c * 16 + h * 8];
                    oT[db] = __builtin_amdgcn_mfma_f32_32x32x16_bf16(vf, pfrag[c], oT[db], 0, 0, 0);
                }
            __builtin_amdgcn_s_setprio(0);
        }

        asm volatile("s_waitcnt lgkmcnt(0)" ::: "memory");
        __builtin_amdgcn_sched_barrier(0);
        __builtin_amdgcn_s_barrier();
        __builtin_amdgcn_sched_barrier(0);
        p ^= 1;
    }

    // ---- epilogue: in-LDS combine of the two KV halves ----
    float lsum = l_lane + __shfl_xor(l_lane, 32);
    float* lsf = (float*)lsBuf;                    // [2][128][65] f32
    const int row = qg * 32 + ql;
#pragma unroll
    for (int db = 0; db < 2; ++db)
#pragma unroll
        for (int r = 0; r < 16; ++r) {
            int d = db * 32 + (r & 3) + 8 * (r >> 2) + 4 * h;
            lsf[(hf * 128 + row) * 65 + d] = oT[db][r];
        }
    if (h == 0) lsf[(hf * 128 + row) * 65 + 64] = lsum;
    __syncthreads();

    const int orow = t >> 2;                       // 0..127
    const int ck = t & 3;
    const float* e0 = lsf + orow * 65;
    const float* e1 = lsf + (128 + orow) * 65;
    const float linv = 1.0f / (e0[64] + e1[64]);
    const int b = bh >> 4, hh = bh & 15;
    const int d0 = ck * 16;
    unsigned short* op = o_ws + ((size_t)b * SS + qp * 128 + orow) * DM + hh * DKH + d0;
    uint4 o0, o1;
    o0.x = (unsigned)cvtpk((e0[d0+0]+e1[d0+0])*linv,  (e0[d0+1]+e1[d0+1])*linv);
    o0.y = (unsigned)cvtpk((e0[d0+2]+e1[d0+2])*linv,  (e0[d0+3]+e1[d0+3])*linv);
    o0.z = (unsigned)cvtpk((e0[d0+4]+e1[d0+4])*linv,  (e0[d0+5]+e1[d0+5])*linv);
    o0.w = (unsigned)cvtpk((e0[d0+6]+e1[d0+6])*linv,  (e0[d0+7]+e1[d0+7])*linv);
    o1.x = (unsigned)cvtpk((e0[d0+8]+e1[d0+8])*linv,  (e0[d0+9]+e1[d0+9])*linv);
    o1.y = (unsigned)cvtpk((e0[d0+10]+e1[d0+10])*linv,(e0[d0+11]+e1[d0+11])*linv);
    o1.z = (unsigned)cvtpk((e0[d0+12]+e1[d0+12])*linv,(e0[d0+13]+e1[d0+13])*linv);
    o1.w = (unsigned)cvtpk((e0[d0+14]+e1[d0+14])*linv,(e0[d0+15]+e1[d0+15])*linv);
    *(uint4*)op = o0;
    *(uint4*)(op + 8) = o1;
}

// ---------------- Output projection: 128x64 tile, 3-buffer counted-vmcnt pipeline ---------
__global__ __launch_bounds__(256) void proj_o_b(
    const unsigned short* __restrict__ A, const unsigned short* __restrict__ W,
    const float* __restrict__ bo, float* __restrict__ out)
{
    __shared__ unsigned short lA[3][128 * 32];
    __shared__ unsigned short lB[3][64 * 32];

    const int t = threadIdx.x;
    const int lane = t & 63, w = t >> 6;
    const int wm = w >> 1, wn = w & 1;
    const int g = lane >> 4, lr = lane & 15;

    const int hid = blockIdx.y * 16 + blockIdx.x;   // 512 blocks
    const int xcd = hid & 7, slot = hid >> 3;       // slot 0..63
    const int mbase = (xcd * 4 + (slot & 3)) * 128; // 32 M-panels
    const int nbase = (slot >> 2) * 64;             // 16 N-panels

    const int srow = lane >> 2;
    const int scol = (lane & 3) * 8;

    v4f acc[4][2];
#pragma unroll
    for (int i = 0; i < 4; ++i)
#pragma unroll
        for (int j = 0; j < 2; ++j)
            acc[i][j] = (v4f){0.f, 0.f, 0.f, 0.f};

    auto stage = [&](int bi, int kb) {   // 3 gl16 per wave
        gl16(A + (size_t)(mbase + w * 16 + srow) * DM + kb + scol,      &lA[bi][w * 512]);
        gl16(A + (size_t)(mbase + 64 + w * 16 + srow) * DM + kb + scol, &lA[bi][(w + 4) * 512]);
        gl16(W + (size_t)(nbase + w * 16 + srow) * DM + kb + scol,      &lB[bi][w * 512]);
    };
    auto compute = [&](int bi) {
        v8bf af[4], bf4[2];
#pragma unroll
        for (int mt = 0; mt < 4; ++mt)
            af[mt] = *(const v8bf*)(&lA[bi][(wm * 64 + mt * 16 + lr) * 32 + g * 8]);
#pragma unroll
        for (int nt = 0; nt < 2; ++nt)
            bf4[nt] = *(const v8bf*)(&lB[bi][(wn * 32 + nt * 16 + lr) * 32 + g * 8]);
#pragma unroll
        for (int mt = 0; mt < 4; ++mt)
#pragma unroll
            for (int nt = 0; nt < 2; ++nt)
                acc[mt][nt] = __builtin_amdgcn_mfma_f32_16x16x32_bf16(af[mt], bf4[nt], acc[mt][nt], 0, 0, 0);
    };

    stage(0, 0);
    stage(1, 32);
    int bcur = 0;
#pragma unroll 1
    for (int ki = 0; ki < 30; ++ki) {
        int bnext = bcur + 2; if (bnext >= 3) bnext -= 3;
        stage(bnext, (ki + 2) * 32);
        asm volatile("s_waitcnt vmcnt(6)" ::: "memory");
        __builtin_amdgcn_sched_barrier(0);
        __builtin_amdgcn_s_barrier();
        __builtin_amdgcn_sched_barrier(0);
        compute(bcur);
        __builtin_amdgcn_sched_barrier(0);
        __builtin_amdgcn_s_barrier();
        bcur = (bcur == 2) ? 0 : bcur + 1;
    }
    asm volatile("s_waitcnt vmcnt(3)" ::: "memory");
    __builtin_amdgcn_sched_barrier(0);
    __builtin_amdgcn_s_barrier();
    __builtin_amdgcn_sched_barrier(0);
    compute(bcur);
    __builtin_amdgcn_sched_barrier(0);
    __builtin_amdgcn_s_barrier();
    bcur = (bcur == 2) ? 0 : bcur + 1;
    asm volatile("s_waitcnt vmcnt(0)" ::: "memory");
    __builtin_amdgcn_sched_barrier(0);
    __builtin_amdgcn_s_barrier();
    __builtin_amdgcn_sched_barrier(0);
    compute(bcur);

#pragma unroll
    for (int nt = 0; nt < 2; ++nt) {
        int e = nbase + wn * 32 + nt * 16 + lr;
        float bval = bo[e];
#pragma unroll
        for (int mt = 0; mt < 4; ++mt) {
#pragma unroll
            for (int r = 0; r < 4; ++r) {
                int m = mbase + wm * 64 + mt * 16 + g * 4 + r;
                out[(size_t)m * DM + e] = acc[mt][nt][r] + bval;
            }
        }
    }
}

extern "C" void kernel_launch(void* const* d_in, const int* in_sizes, int n_in,
                              void* d_out, int out_size, void* d_ws, size_t ws_size,
                              hipStream_t stream) {
    const float* q  = (const float*)d_in[0];
    const float* k  = (const float*)d_in[1];
    const float* v  = (const float*)d_in[2];
    const float* wq = (const float*)d_in[3];
    const float* bq = (const float*)d_in[4];
    const float* wk = (const float*)d_in[5];
    const float* bk = (const float*)d_in[6];
    const float* wv = (const float*)d_in[7];
    const float* bv = (const float*)d_in[8];
    const float* wo = (const float*)d_in[9];
    const float* bo = (const float*)d_in[10];
    float* out = (float*)d_out;

    unsigned short* ws    = (unsigned short*)d_ws;
    unsigned short* q_ws  = ws;                                   // 8 MB
    unsigned short* k_ws  = q_ws + (size_t)MM * DM;               // 8 MB
    unsigned short* vt_ws = k_ws + (size_t)MM * DM;               // 8 MB
    unsigned short* xb    = vt_ws + (size_t)MM * DM;              // 24 MB  [xq|xk|xv]
    unsigned short* wb    = xb + (size_t)3 * MM * DM;             // 8 MB   [wq|wk|wv|wo]
    unsigned short* o_ws  = xb;   // alias: xb dead once proj_qkv_b completes

    cvt_to_bf16<<<dim3(256, 7), 256, 0, stream>>>(q, k, v, wq, wk, wv, wo, xb);
    proj_qkv_b<<<dim3(8, 32, 3), 256, 0, stream>>>(xb, wb, bq, bk, bv, q_ws, k_ws, vt_ws);
    attn_kernel<<<dim3(512), 512, 0, stream>>>(q_ws, k_ws, vt_ws, o_ws);
    proj_o_b<<<dim3(16, 32), 256, 0, stream>>>(o_ws, wb + (size_t)3 * DM * DM, bo, out);
}

// Round 18
// 117.335 us; speedup vs baseline: 1.1822x; 1.0254x over previous
//
#include <hip/hip_runtime.h>
#include <hip/hip_bf16.h>

#define DM 1024
#define NH 16
#define DKH 64
#define BB 2
#define SS 2048
#define MM (BB*SS)   // 4096
#define HKB 1024     // KV half length

typedef __bf16 v8bf __attribute__((ext_vector_type(8)));
typedef float  v4f  __attribute__((ext_vector_type(4)));
typedef float  v16f __attribute__((ext_vector_type(16)));

__device__ __forceinline__ unsigned short f2bf(float f) {
    union { float f; unsigned int u; } v; v.f = f;
    unsigned int u = v.u;
    unsigned int r = (u + 0x7fffu + ((u >> 16) & 1u)) >> 16;
    return (unsigned short)r;
}

__device__ __forceinline__ int cvtpk(float lo, float hi) {
    int r;
    asm("v_cvt_pk_bf16_f32 %0, %1, %2" : "=v"(r) : "v"(lo), "v"(hi));
    return r;
}

__device__ __forceinline__ void pl32swap(int& a, int& b) {
    asm("v_permlane32_swap_b32 %0, %1" : "+v"(a), "+v"(b));
}

__device__ __forceinline__ void gl16(const void* g, void* l) {
    auto gp = reinterpret_cast<const __attribute__((address_space(1))) unsigned int*>(
        reinterpret_cast<uintptr_t>(g));
    auto lp = reinterpret_cast<__attribute__((address_space(3))) unsigned int*>(
        reinterpret_cast<uintptr_t>(l));
    __builtin_amdgcn_global_load_lds(gp, lp, 16, 0, 0);
}

// ---------------- fp32 -> bf16 weight convert: [wq|wk|wv|wo] ------------------------------
__global__ __launch_bounds__(256) void cvt_w(
    const float* __restrict__ wq, const float* __restrict__ wk, const float* __restrict__ wv,
    const float* __restrict__ wo, unsigned short* __restrict__ dst)
{
    const int y = blockIdx.y;
    const float* src = (y == 0) ? wq : (y == 1) ? wk : (y == 2) ? wv : wo;
    unsigned short* d = dst + (size_t)y * DM * DM;
    const size_t n = (size_t)DM * DM;
    const size_t stride = (size_t)gridDim.x * blockDim.x;
    for (size_t i = (size_t)blockIdx.x * blockDim.x + threadIdx.x; i * 8 < n; i += stride) {
        float4 a = ((const float4*)src)[2 * i];
        float4 b = ((const float4*)src)[2 * i + 1];
        uint4 o;
        o.x = (unsigned)cvtpk(a.x, a.y);
        o.y = (unsigned)cvtpk(a.z, a.w);
        o.z = (unsigned)cvtpk(b.x, b.y);
        o.w = (unsigned)cvtpk(b.z, b.w);
        ((uint4*)d)[i] = o;
    }
}

// ---------------- QKV projection: fp32 X reg-staged + bf16 W gl16, counted vmcnt ----------
// z=0: Q (scaled by 0.125*log2e, layout [bh][s][64]); z=1: K; z=2: V^T ([bh][64][s])
__global__ __launch_bounds__(256) void proj_qkv_b(
    const float* __restrict__ Xq, const float* __restrict__ Xk, const float* __restrict__ Xv,
    const unsigned short* __restrict__ wb,
    const float* __restrict__ bq, const float* __restrict__ bk, const float* __restrict__ bv,
    unsigned short* __restrict__ q_ws, unsigned short* __restrict__ k_ws,
    unsigned short* __restrict__ vt_ws)
{
    const int z = blockIdx.z;
    const float* X = (z == 0) ? Xq : (z == 1) ? Xk : Xv;
    const unsigned short* W = wb + (size_t)z * DM * DM;
    const float* bias = (z == 0) ? bq : (z == 1) ? bk : bv;

    __shared__ unsigned short lA[2][128 * 32];
    __shared__ unsigned short lB[3][128 * 32];

    const int t = threadIdx.x;
    const int lane = t & 63, w = t >> 6;
    const int wm = w >> 1, wn = w & 1;
    const int g = lane >> 4, lr = lane & 15;

    // M-major XCD swizzle: xcd owns 4 M-panels x all 8 N-blocks
    const int hid = blockIdx.y * 8 + blockIdx.x;
    const int xcd = hid & 7, slot = hid >> 3;
    const int mbase = (xcd * 4 + (slot & 3)) * 128;
    const int nbase = (slot >> 2) * 128;

    const int srow = lane >> 2;        // 0..15
    const int scol = (lane & 3) * 8;   // 0,8,16,24
    const int arow = t >> 1;           // 0..127
    const int acg  = (t & 1) * 16;     // 0 or 16

    v4f acc[4][4];
#pragma unroll
    for (int i = 0; i < 4; ++i)
#pragma unroll
        for (int j = 0; j < 4; ++j)
            acc[i][j] = (v4f){0.f, 0.f, 0.f, 0.f};

    float4 ar0, ar1, ar2, ar3;
    auto loadA = [&](int kb) {           // 4 x dwordx4 (fp32)
        const float4* p = (const float4*)(X + (size_t)(mbase + arow) * DM + kb + acg);
        ar0 = p[0]; ar1 = p[1]; ar2 = p[2]; ar3 = p[3];
    };
    auto writeA = [&](int bi) {          // 8 cvtpk + 2 ds_write_b128 (auto vmcnt on ar*)
        uint4 o0, o1;
        o0.x = (unsigned)cvtpk(ar0.x, ar0.y); o0.y = (unsigned)cvtpk(ar0.z, ar0.w);
        o0.z = (unsigned)cvtpk(ar1.x, ar1.y); o0.w = (unsigned)cvtpk(ar1.z, ar1.w);
        o1.x = (unsigned)cvtpk(ar2.x, ar2.y); o1.y = (unsigned)cvtpk(ar2.z, ar2.w);
        o1.z = (unsigned)cvtpk(ar3.x, ar3.y); o1.w = (unsigned)cvtpk(ar3.z, ar3.w);
        *(uint4*)&lA[bi][arow * 32 + acg]     = o0;
        *(uint4*)&lA[bi][arow * 32 + acg + 8] = o1;
    };
    auto stageB = [&](int bi, int kb) {  // 2 gl16 per wave
        gl16(W + (size_t)(nbase + w * 16 + srow) * DM + kb + scol,      &lB[bi][w * 512]);
        gl16(W + (size_t)(nbase + 64 + w * 16 + srow) * DM + kb + scol, &lB[bi][(w + 4) * 512]);
    };
    auto compute = [&](const unsigned short* A_, const unsigned short* B_) {
        v8bf af[4], bf4[4];
#pragma unroll
        for (int mt = 0; mt < 4; ++mt)
            af[mt] = *(const v8bf*)(&A_[(wm * 64 + mt * 16 + lr) * 32 + g * 8]);
#pragma unroll
        for (int nt = 0; nt < 4; ++nt)
            bf4[nt] = *(const v8bf*)(&B_[(wn * 64 + nt * 16 + lr) * 32 + g * 8]);
#pragma unroll
        for (int mt = 0; mt < 4; ++mt)
#pragma unroll
            for (int nt = 0; nt < 4; ++nt)
                acc[mt][nt] = __builtin_amdgcn_mfma_f32_16x16x32_bf16(af[mt], bf4[nt], acc[mt][nt], 0, 0, 0);
    };

    // prologue: A(0)->regs, B(0) in flight; write A(0); A(1),B(1) in flight
    loadA(0);
    stageB(0, 0);
    writeA(0);          // compiler inserts vmcnt wait for ar* (loadA(0))
    loadA(32);
    stageB(1, 32);

#pragma unroll 1
    for (int ki = 0; ki < 31; ++ki) {
        writeA((ki + 1) & 1);                    // A(ki+1); auto-waits its loads
        if (ki < 30) {
            loadA((ki + 2) * 32);
            stageB((ki + 2) % 3, (ki + 2) * 32);
            asm volatile("s_waitcnt vmcnt(6) lgkmcnt(0)" ::: "memory");  // B(ki+1) done
        } else {
            asm volatile("s_waitcnt vmcnt(0) lgkmcnt(0)" ::: "memory");  // B(31) done
        }
        __builtin_amdgcn_sched_barrier(0);
        __builtin_amdgcn_s_barrier();
        __builtin_amdgcn_sched_barrier(0);
        compute(lA[ki & 1], lB[ki % 3]);
        __builtin_amdgcn_sched_barrier(0);
        __builtin_amdgcn_s_barrier();
    }
    compute(lA[31 & 1], lB[31 % 3]);

    const float scale = (z == 0) ? 0.18033688011112042f : 1.0f;  // 0.125*log2(e) for Q
#pragma unroll
    for (int nt = 0; nt < 4; ++nt) {
        int e = nbase + wn * 64 + nt * 16 + lr;
        float bval = bias[e];
        int h = e >> 6, dk = e & 63;
#pragma unroll
        for (int mt = 0; mt < 4; ++mt) {
#pragma unroll
            for (int r = 0; r < 4; ++r) {
                int m = mbase + wm * 64 + mt * 16 + g * 4 + r;
                float val = (acc[mt][nt][r] + bval) * scale;
                unsigned short o = f2bf(val);
                int b = m >> 11, s = m & 2047;
                if (z == 2) {
                    vt_ws[((size_t)(b * NH + h) * DKH + dk) * SS + s] = o;
                } else {
                    unsigned short* dst = (z == 0) ? q_ws : k_ws;
                    dst[((size_t)(b * NH + h) * SS + s) * DKH + dk] = o;
                }
            }
        }
    }
}

// ------------- Flash attention v6: sm-split per kb (exp/pack kb1 overlaps PV kb0) ---------
#define KB 64
#define LDP 72
#define TILE 4608   // shorts per 64x64 tile with pad

__global__ __launch_bounds__(512, 4) void attn_kernel(
    const unsigned short* __restrict__ q_ws, const unsigned short* __restrict__ k_ws,
    const unsigned short* __restrict__ vt_ws, unsigned short* __restrict__ o_ws)
{
    __shared__ __align__(16) unsigned short lsBuf[2 * 4 * TILE];   // 73728 B

    const int t = threadIdx.x, l = t & 63, w = t >> 6;   // w 0..7
    const int h = l >> 5, ql = l & 31;
    const int qg = w >> 1, hf = w & 1;

    const int hid = blockIdx.x;
    const int slot = hid >> 3;
    const int bh = (hid & 7) * 4 + (slot & 3);
    const int qp = slot >> 2;              // 0..15, 128 q rows each
    const int q0 = qp * 128 + qg * 32;

    const unsigned short* Kb = k_ws + (size_t)bh * SS * DKH;
    const unsigned short* Vb = vt_ws + (size_t)bh * DKH * SS;

    v8bf qf[4];
#pragma unroll
    for (int c = 0; c < 4; ++c)
        qf[c] = *(const v8bf*)(q_ws + ((size_t)bh * SS + q0 + ql) * DKH + c * 16 + h * 8);

    v16f oT[2];
#pragma unroll
    for (int d = 0; d < 2; ++d)
#pragma unroll
        for (int r = 0; r < 16; ++r) oT[d][r] = 0.f;
    float l_lane = 0.f;
    const v16f z16 = {};

    const int r0s = t >> 3, c0s = (t & 7) * 8;
    uint4 k0r, k1r, v0r, v1r;

    k0r = *(const uint4*)(Kb + (size_t)(r0s) * DKH + c0s);
    v0r = *(const uint4*)(Vb + (size_t)r0s * SS + c0s);
    k1r = *(const uint4*)(Kb + (size_t)(HKB + r0s) * DKH + c0s);
    v1r = *(const uint4*)(Vb + (size_t)r0s * SS + HKB + c0s);
    {
        unsigned short* B0 = lsBuf;
        *(uint4*)&B0[0 * TILE + r0s * LDP + c0s] = k0r;
        *(uint4*)&B0[1 * TILE + r0s * LDP + c0s] = v0r;
        *(uint4*)&B0[2 * TILE + r0s * LDP + c0s] = k1r;
        *(uint4*)&B0[3 * TILE + r0s * LDP + c0s] = v1r;
    }
    k0r = *(const uint4*)(Kb + (size_t)(KB + r0s) * DKH + c0s);
    v0r = *(const uint4*)(Vb + (size_t)r0s * SS + KB + c0s);
    k1r = *(const uint4*)(Kb + (size_t)(HKB + KB + r0s) * DKH + c0s);
    v1r = *(const uint4*)(Vb + (size_t)r0s * SS + HKB + KB + c0s);
    asm volatile("s_waitcnt lgkmcnt(0)" ::: "memory");
    __builtin_amdgcn_sched_barrier(0);
    __builtin_amdgcn_s_barrier();
    __builtin_amdgcn_sched_barrier(0);

    const int NT = 16;
    int p = 0;
    for (int tt = 0; tt < NT; ++tt) {
        unsigned short* Kp = lsBuf + p * (4 * TILE) + hf * (2 * TILE);
        unsigned short* Vp = Kp + TILE;
        if (tt + 1 < NT) {
            unsigned short* Bn = lsBuf + (p ^ 1) * (4 * TILE);
            *(uint4*)&Bn[0 * TILE + r0s * LDP + c0s] = k0r;
            *(uint4*)&Bn[1 * TILE + r0s * LDP + c0s] = v0r;
            *(uint4*)&Bn[2 * TILE + r0s * LDP + c0s] = k1r;
            *(uint4*)&Bn[3 * TILE + r0s * LDP + c0s] = v1r;
        }
        if (tt + 2 < NT) {
            int kt2 = (tt + 2) * KB;
            k0r = *(const uint4*)(Kb + (size_t)(kt2 + r0s) * DKH + c0s);
            v0r = *(const uint4*)(Vb + (size_t)r0s * SS + kt2 + c0s);
            k1r = *(const uint4*)(Kb + (size_t)(HKB + kt2 + r0s) * DKH + c0s);
            v1r = *(const uint4*)(Vb + (size_t)r0s * SS + HKB + kt2 + c0s);
        }

        // ---- S^T = K . Q^T (zero-C first MFMA) ----
        v16f sT[2];
        __builtin_amdgcn_s_setprio(1);
#pragma unroll
        for (int kb = 0; kb < 2; ++kb) {
            v8bf kf = *(const v8bf*)&Kp[(kb * 32 + ql) * LDP + h * 8];
            sT[kb] = __builtin_amdgcn_mfma_f32_32x32x16_bf16(kf, qf[0], z16, 0, 0, 0);
        }
#pragma unroll
        for (int c = 1; c < 4; ++c)
#pragma unroll
            for (int kb = 0; kb < 2; ++kb) {
                v8bf kf = *(const v8bf*)&Kp[(kb * 32 + ql) * LDP + c * 16 + h * 8];
                sT[kb] = __builtin_amdgcn_mfma_f32_32x32x16_bf16(kf, qf[c], sT[kb], 0, 0, 0);
            }
        __builtin_amdgcn_s_setprio(0);

        // ---- sm-split: per-kb {exp -> pack -> PV} so kb1's VALU overlaps PV kb0 ----
        v8bf pfrag[4];
#pragma unroll
        for (int kb = 0; kb < 2; ++kb) {
            float rs0 = 0.f, rs1 = 0.f, rs2 = 0.f, rs3 = 0.f;
#pragma unroll
            for (int r = 0; r < 16; r += 4) {
                float e0 = __builtin_amdgcn_exp2f(sT[kb][r + 0]);
                float e1 = __builtin_amdgcn_exp2f(sT[kb][r + 1]);
                float e2 = __builtin_amdgcn_exp2f(sT[kb][r + 2]);
                float e3 = __builtin_amdgcn_exp2f(sT[kb][r + 3]);
                sT[kb][r + 0] = e0; sT[kb][r + 1] = e1;
                sT[kb][r + 2] = e2; sT[kb][r + 3] = e3;
                rs0 += e0; rs1 += e1; rs2 += e2; rs3 += e3;
            }
            l_lane += (rs0 + rs1) + (rs2 + rs3);

#pragma unroll
            for (int cc = 0; cc < 2; ++cc) {
                int A0 = cvtpk(sT[kb][8 * cc + 0], sT[kb][8 * cc + 1]);
                int A1 = cvtpk(sT[kb][8 * cc + 2], sT[kb][8 * cc + 3]);
                int B0 = cvtpk(sT[kb][8 * cc + 4], sT[kb][8 * cc + 5]);
                int B1 = cvtpk(sT[kb][8 * cc + 6], sT[kb][8 * cc + 7]);
                pl32swap(A0, B0);
                pl32swap(A1, B1);
                union { int i[4]; v8bf v; } u;
                u.i[0] = A0; u.i[1] = A1; u.i[2] = B0; u.i[3] = B1;
                pfrag[kb * 2 + cc] = u.v;
            }

            __builtin_amdgcn_s_setprio(1);
#pragma unroll
            for (int db = 0; db < 2; ++db)
#pragma unroll
                for (int cc = 0; cc < 2; ++cc) {
                    int c = kb * 2 + cc;
                    v8bf vf = *(const v8bf*)&Vp[(db * 32 + ql) * LDP + c * 16 + h * 8];
                    oT[db] = __builtin_amdgcn_mfma_f32_32x32x16_bf16(vf, pfrag[c], oT[db], 0, 0, 0);
                }
            __builtin_amdgcn_s_setprio(0);
        }

        asm volatile("s_waitcnt lgkmcnt(0)" ::: "memory");
        __builtin_amdgcn_sched_barrier(0);
        __builtin_amdgcn_s_barrier();
        __builtin_amdgcn_sched_barrier(0);
        p ^= 1;
    }

    // ---- epilogue: in-LDS combine of the two KV halves ----
    float lsum = l_lane + __shfl_xor(l_lane, 32);
    float* lsf = (float*)lsBuf;                    // [2][128][65] f32
    const int row = qg * 32 + ql;
#pragma unroll
    for (int db = 0; db < 2; ++db)
#pragma unroll
        for (int r = 0; r < 16; ++r) {
            int d = db * 32 + (r & 3) + 8 * (r >> 2) + 4 * h;
            lsf[(hf * 128 + row) * 65 + d] = oT[db][r];
        }
    if (h == 0) lsf[(hf * 128 + row) * 65 + 64] = lsum;
    __syncthreads();

    const int orow = t >> 2;                       // 0..127
    const int ck = t & 3;
    const float* e0 = lsf + orow * 65;
    const float* e1 = lsf + (128 + orow) * 65;
    const float linv = 1.0f / (e0[64] + e1[64]);
    const int b = bh >> 4, hh = bh & 15;
    const int d0 = ck * 16;
    unsigned short* op = o_ws + ((size_t)b * SS + qp * 128 + orow) * DM + hh * DKH + d0;
    uint4 o0, o1;
    o0.x = (unsigned)cvtpk((e0[d0+0]+e1[d0+0])*linv,  (e0[d0+1]+e1[d0+1])*linv);
    o0.y = (unsigned)cvtpk((e0[d0+2]+e1[d0+2])*linv,  (e0[d0+3]+e1[d0+3])*linv);
    o0.z = (unsigned)cvtpk((e0[d0+4]+e1[d0+4])*linv,  (e0[d0+5]+e1[d0+5])*linv);
    o0.w = (unsigned)cvtpk((e0[d0+6]+e1[d0+6])*linv,  (e0[d0+7]+e1[d0+7])*linv);
    o1.x = (unsigned)cvtpk((e0[d0+8]+e1[d0+8])*linv,  (e0[d0+9]+e1[d0+9])*linv);
    o1.y = (unsigned)cvtpk((e0[d0+10]+e1[d0+10])*linv,(e0[d0+11]+e1[d0+11])*linv);
    o1.z = (unsigned)cvtpk((e0[d0+12]+e1[d0+12])*linv,(e0[d0+13]+e1[d0+13])*linv);
    o1.w = (unsigned)cvtpk((e0[d0+14]+e1[d0+14])*linv,(e0[d0+15]+e1[d0+15])*linv);
    *(uint4*)op = o0;
    *(uint4*)(op + 8) = o1;
}

// ---------------- Output projection: 128x64 tile, 3-buffer counted-vmcnt pipeline ---------
__global__ __launch_bounds__(256) void proj_o_b(
    const unsigned short* __restrict__ A, const unsigned short* __restrict__ W,
    const float* __restrict__ bo, float* __restrict__ out)
{
    __shared__ unsigned short lA[3][128 * 32];
    __shared__ unsigned short lB[3][64 * 32];

    const int t = threadIdx.x;
    const int lane = t & 63, w = t >> 6;
    const int wm = w >> 1, wn = w & 1;
    const int g = lane >> 4, lr = lane & 15;

    const int hid = blockIdx.y * 16 + blockIdx.x;   // 512 blocks
    const int xcd = hid & 7, slot = hid >> 3;       // slot 0..63
    const int mbase = (xcd * 4 + (slot & 3)) * 128; // 32 M-panels
    const int nbase = (slot >> 2) * 64;             // 16 N-panels

    const int srow = lane >> 2;
    const int scol = (lane & 3) * 8;

    v4f acc[4][2];
#pragma unroll
    for (int i = 0; i < 4; ++i)
#pragma unroll
        for (int j = 0; j < 2; ++j)
            acc[i][j] = (v4f){0.f, 0.f, 0.f, 0.f};

    auto stage = [&](int bi, int kb) {   // 3 gl16 per wave
        gl16(A + (size_t)(mbase + w * 16 + srow) * DM + kb + scol,      &lA[bi][w * 512]);
        gl16(A + (size_t)(mbase + 64 + w * 16 + srow) * DM + kb + scol, &lA[bi][(w + 4) * 512]);
        gl16(W + (size_t)(nbase + w * 16 + srow) * DM + kb + scol,      &lB[bi][w * 512]);
    };
    auto compute = [&](int bi) {
        v8bf af[4], bf4[2];
#pragma unroll
        for (int mt = 0; mt < 4; ++mt)
            af[mt] = *(const v8bf*)(&lA[bi][(wm * 64 + mt * 16 + lr) * 32 + g * 8]);
#pragma unroll
        for (int nt = 0; nt < 2; ++nt)
            bf4[nt] = *(const v8bf*)(&lB[bi][(wn * 32 + nt * 16 + lr) * 32 + g * 8]);
#pragma unroll
        for (int mt = 0; mt < 4; ++mt)
#pragma unroll
            for (int nt = 0; nt < 2; ++nt)
                acc[mt][nt] = __builtin_amdgcn_mfma_f32_16x16x32_bf16(af[mt], bf4[nt], acc[mt][nt], 0, 0, 0);
    };

    stage(0, 0);
    stage(1, 32);
    int bcur = 0;
#pragma unroll 1
    for (int ki = 0; ki < 30; ++ki) {
        int bnext = bcur + 2; if (bnext >= 3) bnext -= 3;
        stage(bnext, (ki + 2) * 32);
        asm volatile("s_waitcnt vmcnt(6)" ::: "memory");
        __builtin_amdgcn_sched_barrier(0);
        __builtin_amdgcn_s_barrier();
        __builtin_amdgcn_sched_barrier(0);
        compute(bcur);
        __builtin_amdgcn_sched_barrier(0);
        __builtin_amdgcn_s_barrier();
        bcur = (bcur == 2) ? 0 : bcur + 1;
    }
    asm volatile("s_waitcnt vmcnt(3)" ::: "memory");
    __builtin_amdgcn_sched_barrier(0);
    __builtin_amdgcn_s_barrier();
    __builtin_amdgcn_sched_barrier(0);
    compute(bcur);
    __builtin_amdgcn_sched_barrier(0);
    __builtin_amdgcn_s_barrier();
    bcur = (bcur == 2) ? 0 : bcur + 1;
    asm volatile("s_waitcnt vmcnt(0)" ::: "memory");
    __builtin_amdgcn_sched_barrier(0);
    __builtin_amdgcn_s_barrier();
    __builtin_amdgcn_sched_barrier(0);
    compute(bcur);

#pragma unroll
    for (int nt = 0; nt < 2; ++nt) {
        int e = nbase + wn * 32 + nt * 16 + lr;
        float bval = bo[e];
#pragma unroll
        for (int mt = 0; mt < 4; ++mt) {
#pragma unroll
            for (int r = 0; r < 4; ++r) {
                int m = mbase + wm * 64 + mt * 16 + g * 4 + r;
                out[(size_t)m * DM + e] = acc[mt][nt][r] + bval;
            }
        }
    }
}

extern "C" void kernel_launch(void* const* d_in, const int* in_sizes, int n_in,
                              void* d_out, int out_size, void* d_ws, size_t ws_size,
                              hipStream_t stream) {
    const float* q  = (const float*)d_in[0];
    const float* k  = (const float*)d_in[1];
    const float* v  = (const float*)d_in[2];
    const float* wq = (const float*)d_in[3];
    const float* bq = (const float*)d_in[4];
    const float* wk = (const float*)d_in[5];
    const float* bk = (const float*)d_in[6];
    const float* wv = (const float*)d_in[7];
    const float* bv = (const float*)d_in[8];
    const float* wo = (const float*)d_in[9];
    const float* bo = (const float*)d_in[10];
    float* out = (float*)d_out;

    unsigned short* ws    = (unsigned short*)d_ws;
    unsigned short* q_ws  = ws;                                   // 8 MB
    unsigned short* k_ws  = q_ws + (size_t)MM * DM;               // 8 MB
    unsigned short* vt_ws = k_ws + (size_t)MM * DM;               // 8 MB
    unsigned short* wb    = vt_ws + (size_t)MM * DM;              // 8 MB [wq|wk|wv|wo]
    unsigned short* o_ws  = wb + (size_t)4 * DM * DM;             // 8 MB

    cvt_w<<<dim3(64, 4), 256, 0, stream>>>(wq, wk, wv, wo, wb);
    proj_qkv_b<<<dim3(8, 32, 3), 256, 0, stream>>>(q, k, v, wb, bq, bk, bv, q_ws, k_ws, vt_ws);
    attn_kernel<<<dim3(512), 512, 0, stream>>>(q_ws, k_ws, vt_ws, o_ws);
    proj_o_b<<<dim3(16, 32), 256, 0, stream>>>(o_ws, wb + (size_t)3 * DM * DM, bo, out);
}